// Round 4
// baseline (7520.042 us; speedup 1.0000x reference)
//
#include <hip/hip_runtime.h>
#include <hip/hip_bf16.h>

typedef float f32x4 __attribute__((ext_vector_type(4)));

// ---- workspace layout (bytes) ----
static constexpr size_t WS_LOSSP = 0;         // double[2048]               -> 16384
static constexpr size_t WS_B32   = 294912;    // float[32768] np-exact B    -> 425984
static constexpr size_t WS_IDX   = 425984;    // int[65536]                 -> 688128
static constexpr size_t WS_CNT   = 688128;    // int[65536] cand counts     -> 950272
static constexpr size_t WS_LST   = 950272;    // ushort[65536*16] cand list -> 3047424
static constexpr size_t WS_XH    = 3145728;   // float[8*256*8192] 64MB     -> 70254592
static constexpr size_t WS_CBT   = 70254592;  // ushort bf16[8*256*4096]    -> 87031808

#define DELTA 3.0e-4f

__device__ inline float b2f(unsigned short u) {
  unsigned int i = ((unsigned int)u) << 16; return __uint_as_float(i);
}
__device__ inline unsigned int fkey(float f) {
  unsigned int b = __float_as_uint(f); return (b & 0x80000000u) ? ~b : (b | 0x80000000u);
}
__device__ inline float funkey(unsigned int u) {
  unsigned int b = (u & 0x80000000u) ? (u ^ 0x80000000u) : ~u; return __uint_as_float(b);
}

// numpy pairwise_sum of 256 SQUARES, AVX512 width-16 emulation:
// n=256 -> split 128+128; each 128 = 8 zmm loads r0..r7,
// combine ((r0+r1)+(r2+r3))+((r4+r5)+(r6+r7)), then GCC _mm512_reduce_add_ps:
// u_i=V_i+V_{8+i}; w_i=u_i+u_{4+i}; (w0+w2)+(w1+w3)
__device__ inline float np_pw256sq(const float* p, int stride) {
#pragma clang fp contract(off)
  float h2[2];
#pragma unroll
  for (int hh = 0; hh < 2; ++hh) {
    const float* q = p + (size_t)(hh * 128) * stride;
    float V[16];
#pragma unroll
    for (int i = 0; i < 16; ++i) {
      float e[8];
#pragma unroll
      for (int j = 0; j < 8; ++j) { float x = q[(size_t)(j * 16 + i) * stride]; e[j] = x * x; }
      float t01 = e[0] + e[1], t23 = e[2] + e[3], t45 = e[4] + e[5], t67 = e[6] + e[7];
      float ta = t01 + t23, tb = t45 + t67;
      V[i] = ta + tb;
    }
    float u[8];
#pragma unroll
    for (int i = 0; i < 8; ++i) u[i] = V[i] + V[8 + i];
    float w[4];
#pragma unroll
    for (int i = 0; i < 4; ++i) w[i] = u[i] + u[4 + i];
    float wa = w[0] + w[2], wb = w[1] + w[3];
    h2[hh] = wa + wb;
  }
  return h2[0] + h2[1];
}

// ---------- np-exact codebook row norms ----------
__global__ __launch_bounds__(256) void k_cbnormB(const float* __restrict__ cb,
                                                 float* __restrict__ B32) {
  int row = blockIdx.x * 256 + threadIdx.x;      // grid 128 -> 32768 rows
  B32[row] = np_pw256sq(cb + (size_t)row * 256, 1);
}

// ---------- transpose codebooks to bf16: CBTb[m][c][k] ----------
__global__ __launch_bounds__(256) void k_cbtb(const float* __restrict__ cb,
                                              unsigned short* __restrict__ cbt) {
  int bx = blockIdx.x;                 // grid 2048 = m(8) * kt(64) * ct(4)
  int ct = bx & 3, kt = (bx >> 2) & 63, m = bx >> 8;
  __shared__ float tile[64][65];
  int tid = threadIdx.x, rr = tid >> 4, cq = tid & 15;
  const float* src = cb + ((size_t)(m * 4096 + kt * 64)) * 256 + ct * 64;
#pragma unroll
  for (int p = 0; p < 4; ++p) {
    int kr = p * 16 + rr;
    f32x4 v = *(const f32x4*)(src + (size_t)kr * 256 + cq * 4);
    tile[kr][cq*4+0]=v[0]; tile[kr][cq*4+1]=v[1]; tile[kr][cq*4+2]=v[2]; tile[kr][cq*4+3]=v[3];
  }
  __syncthreads();
  unsigned short* dst = cbt + ((size_t)(m * 256 + ct * 64)) * 4096 + kt * 64;
#pragma unroll
  for (int p = 0; p < 4; ++p) {
    int cr = p * 16 + rr;
    unsigned int pk[2];
#pragma unroll
    for (int e = 0; e < 2; ++e) {
      __hip_bfloat16 h0 = __float2bfloat16(tile[cq*4 + e*2 + 0][cr]);
      __hip_bfloat16 h1 = __float2bfloat16(tile[cq*4 + e*2 + 1][cr]);
      unsigned int u0 = *reinterpret_cast<unsigned short*>(&h0);
      unsigned int u1 = *reinterpret_cast<unsigned short*>(&h1);
      pk[e] = u0 | (u1 << 16);
    }
    *(uint2*)(dst + (size_t)cr * 4096 + cq * 4) = make_uint2(pk[0], pk[1]);
  }
}

// ---------- x-hat: np.einsum-exact (sequential d, no FMA), stored XH[m][c][t] ----------
__global__ __launch_bounds__(256) void k_xhat(const float* __restrict__ slots,
                                              const float* __restrict__ Wp,
                                              const float* __restrict__ bp,
                                              float* __restrict__ XH) {
#pragma clang fp contract(off)
  int bx = blockIdx.x;                 // grid 65536 = m(8) * cg(32) * tt(256)
  int m = bx & 7, cg = (bx >> 3) & 31, tt = bx >> 8;
  int t0 = tt * 32, c0 = cg * 8;
  __shared__ float Ls[32 * 257];
  __shared__ float Wt[256 * 8];
  int tid = threadIdx.x;
  {
    int r = tid >> 3, q = tid & 7;     // 32 rows x 8 segments of 32 floats
    const float* src = slots + (size_t)(t0 + r) * 2048 + m * 256 + q * 32;
    float* dstrow = &Ls[r * 257 + q * 32];
#pragma unroll
    for (int e = 0; e < 8; ++e) {
      f32x4 v = *(const f32x4*)(src + e * 4);
      dstrow[e*4+0]=v[0]; dstrow[e*4+1]=v[1]; dstrow[e*4+2]=v[2]; dstrow[e*4+3]=v[3];
    }
  }
  {
    const float* wsrc = Wp + (size_t)m * 65536 + (size_t)tid * 256 + c0;
    f32x4 w0 = *(const f32x4*)(wsrc);
    f32x4 w1 = *(const f32x4*)(wsrc + 4);
    *(f32x4*)&Wt[tid * 8]     = w0;
    *(f32x4*)&Wt[tid * 8 + 4] = w1;
  }
  __syncthreads();
  int tl = tid & 31, cl = tid >> 5;    // 32 tokens x 8 channels
  const float* lsrow = &Ls[tl * 257];
  float acc = 0.0f;
  for (int d = 0; d < 256; ++d) {
    float p = lsrow[d] * Wt[d * 8 + cl];   // separate mul
    acc = acc + p;                          // separate add, strict order
  }
  float xv = acc + bp[m * 256 + c0 + cl];
  XH[(size_t)m * 2097152 + (size_t)(c0 + cl) * 8192 + t0 + tl] = xv;
}

// ---------- fast f32 scan: per-token LDS candidate lists within DELTA of running min ----------
__global__ __launch_bounds__(256) void k_argmin(const float* __restrict__ XH,
                                                const unsigned short* __restrict__ CBTb,
                                                const float* __restrict__ B32,
                                                int* __restrict__ cnts,
                                                unsigned short* __restrict__ lists) {
  int bx = blockIdx.x;                 // grid 1024 = tt(128) * m(8); m=bx&7 -> XCD affinity
  int m = bx & 7, tt = bx >> 3;
  int t0 = tt * 64;
  __shared__ float XT[16384];          // [256 c][64 t] 64KB
  __shared__ float CBc[4096];          // [64 c][64 k] 16KB
  __shared__ unsigned int umin[64];
  __shared__ int lcnt[64];
  __shared__ unsigned short llist[64][16];
  int tid = threadIdx.x;
  const float* xsrc = XH + (size_t)m * 2097152;
#pragma unroll
  for (int i = 0; i < 16; ++i) {
    int f = tid + 256 * i;             // 4096 float4
    int c = f >> 4, to = (f & 15) * 4;
    *(f32x4*)&XT[f * 4] = *(const f32x4*)(xsrc + (size_t)c * 8192 + t0 + to);
  }
  if (tid < 64) { umin[tid] = 0xFFFFFFFFu; lcnt[tid] = 0; }
  int tg = tid & 15, kg = tid >> 4;    // 16 tok-groups x 16 k-groups
  const unsigned short* cbase = CBTb + (size_t)m * 1048576;
  const float* nbase = B32 + m * 4096;

  for (int pass = 0; pass < 2; ++pass) {
    int kchi = (pass == 0) ? 1 : 64;   // pass0: warm-up on kc=0 (min only)
    for (int kc = 0; kc < kchi; ++kc) {
      float acc[4][4] = {};
      for (int c4 = 0; c4 < 4; ++c4) {
        __syncthreads();               // also covers XT staging / umin init on first iter
#pragma unroll
        for (int i = 0; i < 4; ++i) {
          int f = tid + 256 * i;       // 1024 groups of 4 bf16
          int cc = f >> 4, ko = (f & 15) * 4;
          uint2 raw = *(const uint2*)(cbase + (size_t)(c4*64+cc)*4096 + kc*64 + ko);
          CBc[f*4+0] = b2f((unsigned short)(raw.x & 0xFFFF));
          CBc[f*4+1] = b2f((unsigned short)(raw.x >> 16));
          CBc[f*4+2] = b2f((unsigned short)(raw.y & 0xFFFF));
          CBc[f*4+3] = b2f((unsigned short)(raw.y >> 16));
        }
        __syncthreads();
#pragma unroll 8
        for (int c = 0; c < 64; ++c) {
          f32x4 xv = *(const f32x4*)&XT[(c4 * 64 + c) * 64 + tg * 4];
          f32x4 bv = *(const f32x4*)&CBc[c * 64 + kg * 4];
#pragma unroll
          for (int i = 0; i < 4; ++i) {
            acc[i][0] += xv[i]*bv[0]; acc[i][1] += xv[i]*bv[1];
            acc[i][2] += xv[i]*bv[2]; acc[i][3] += xv[i]*bv[3];
          }
        }
      }
      f32x4 cn = *(const f32x4*)(nbase + kc * 64 + kg * 4);
#pragma unroll
      for (int i = 0; i < 4; ++i) {
        int tok = tg * 4 + i;
#pragma unroll
        for (int jj = 0; jj < 4; ++jj) {
          float s = cn[jj] - 2.0f * acc[i][jj];
          unsigned int key = fkey(s);
          if (pass == 0) {
            atomicMin(&umin[tok], key);
          } else {
            unsigned int cur = *((volatile unsigned int*)&umin[tok]);
            float smin = funkey(cur);
            if (s <= smin + DELTA) {   // superset-safe: threshold only ever too loose
              int k = kc * 64 + kg * 4 + jj;
              int pos = atomicAdd(&lcnt[tok], 1);
              if (pos < 16) llist[tok][pos] = (unsigned short)k;
            }
            if (key < cur) atomicMin(&umin[tok], key);
          }
        }
      }
    }
  }
  __syncthreads();
  if (tid < 64) cnts[(t0 + tid) * 8 + m] = lcnt[tid];
  {
    int e = tid;                       // 256 threads copy 1024 entries
#pragma unroll
    for (int r = 0; r < 4; ++r, e += 256) {
      int tok = e >> 4, pos = e & 15;
      lists[((size_t)((t0 + tok) * 8 + m)) * 16 + pos] = llist[tok][pos];
    }
  }
}

// ---------- np-f32-exact final selection among candidates ----------
__global__ __launch_bounds__(256) void k_select(const float* __restrict__ XH,
                                                const float* __restrict__ cb,
                                                const float* __restrict__ B32,
                                                const int* __restrict__ cnts,
                                                const unsigned short* __restrict__ lists,
                                                int* __restrict__ idxp) {
#pragma clang fp contract(off)
  int bx = blockIdx.x;                 // grid 1024 = tt(128) * m(8)
  int m = bx & 7, tt = bx >> 3;
  int t0 = tt * 64;
  __shared__ float XT2[256 * 65];      // padded [c][t]
  __shared__ float Atok[64];
  int tid = threadIdx.x;
  const float* xsrc = XH + (size_t)m * 2097152;
#pragma unroll
  for (int i = 0; i < 16; ++i) {
    int f = tid + 256 * i;
    int c = f >> 4, to = (f & 15) * 4;
    f32x4 v = *(const f32x4*)(xsrc + (size_t)c * 8192 + t0 + to);
    XT2[c*65+to+0]=v[0]; XT2[c*65+to+1]=v[1]; XT2[c*65+to+2]=v[2]; XT2[c*65+to+3]=v[3];
  }
  __syncthreads();
  if (tid < 64) Atok[tid] = np_pw256sq(&XT2[tid], 65);   // np.sum(x*x) emulation
  __syncthreads();
  int q = tid >> 2, j = tid & 3;       // 64 quads (token t0+q) x 4 SSE lanes
  int t8m = (t0 + q) * 8 + m;
  int n = cnts[t8m];
  const float* cbm = cb + (size_t)m * 1048576;
  float A = Atok[q];
  float best = __builtin_inff();
  int bk = 0;
  auto eval = [&](int k) {
#pragma clang fp contract(off)
    // SSE contig_outstride0_two emulation: one 4-lane accumulator, 2 adds per 8 elems
    const float* row = cbm + (size_t)k * 256;
    float s = 0.0f;
    for (int i8 = 0; i8 < 256; i8 += 8) {
      float p0 = XT2[(i8 + j) * 65 + q] * row[i8 + j];
      s = s + p0;
      float p1 = XT2[(i8 + 4 + j) * 65 + q] * row[i8 + 4 + j];
      s = s + p1;
    }
    // numpy SSE horizontal reduce: (s0+s1)+(s2+s3)
    float o  = __shfl_xor(s, 1, 64);
    float ts = s + o;                  // lane j: s_j + s_{j^1}
    float o2 = __shfl_xor(ts, 2, 64);
    float red = ts + o2;               // (s0+s1)+(s2+s3), same value on all 4 lanes
    float T1 = A + B32[m * 4096 + k];  // fl(A + Bk)
    float d2 = T1 - 2.0f * red;        // fl(T1 - fl(2E))
    if (d2 < best || (d2 == best && k < bk)) { best = d2; bk = k; }
  };
  if (n <= 16) {
    for (int ci = 0; ci < n; ++ci) eval((int)lists[(size_t)t8m * 16 + ci] & 4095);
  } else {
    for (int k = 0; k < 4096; ++k) eval(k);   // rare overflow: exact full scan
  }
  if (j == 0) idxp[t8m] = bk;
}

// ---------- out = q@Wo + bo (f32), plus per-block loss partials ----------
__global__ __launch_bounds__(256) void k_out(const float* __restrict__ cb,
                                             const float* __restrict__ Wo,
                                             const float* __restrict__ bo,
                                             const float* __restrict__ XH,
                                             const int* __restrict__ idxp,
                                             float* __restrict__ outp,
                                             double* __restrict__ lossp) {
  int bx = blockIdx.x;                 // grid 2048 = tt(256) * m(8)
  int m = bx & 7, tt = bx >> 3;
  int t0 = tt * 32;
  __shared__ float qT[256 * 32];       // [c][t] 32KB
  __shared__ float Wl[64 * 256];       // [c][d] 64KB
  __shared__ double red[256];
  int tid = threadIdx.x;
  {
    int tok = tid & 31, g = tid >> 5;
    int ix = idxp[(size_t)(t0 + tok) * 8 + m] & 4095;   // clamp: no OOB possible
    const float* qrow = cb + ((size_t)m * 4096 + ix) * 256;
#pragma unroll
    for (int i = 0; i < 8; ++i) {
      int c = (g * 8 + i) * 4;
      f32x4 v = *(const f32x4*)(qrow + c);
      qT[(c+0)*32+tok]=v[0]; qT[(c+1)*32+tok]=v[1]; qT[(c+2)*32+tok]=v[2]; qT[(c+3)*32+tok]=v[3];
    }
  }
  int tg = tid & 7, dg = tid >> 3;     // 8 tok-groups(4 tok) x 32 d-groups(8 d)
  float acc[4][8] = {};
  const float* wbase = Wo + (size_t)m * 65536;
  for (int c4 = 0; c4 < 4; ++c4) {
    __syncthreads();
#pragma unroll
    for (int i = 0; i < 16; ++i) {
      int f = tid + 256 * i;
      int cr = f >> 6, doff = (f & 63) * 4;
      *(f32x4*)&Wl[f * 4] = *(const f32x4*)(wbase + (size_t)(c4 * 64 + cr) * 256 + doff);
    }
    __syncthreads();
#pragma unroll 4
    for (int c = 0; c < 64; ++c) {
      f32x4 q4 = *(const f32x4*)&qT[(c4 * 64 + c) * 32 + tg * 4];
      f32x4 w0 = *(const f32x4*)&Wl[c * 256 + dg * 8];
      f32x4 w1 = *(const f32x4*)&Wl[c * 256 + dg * 8 + 4];
#pragma unroll
      for (int i = 0; i < 4; ++i) {
        acc[i][0]+=q4[i]*w0[0]; acc[i][1]+=q4[i]*w0[1]; acc[i][2]+=q4[i]*w0[2]; acc[i][3]+=q4[i]*w0[3];
        acc[i][4]+=q4[i]*w1[0]; acc[i][5]+=q4[i]*w1[1]; acc[i][6]+=q4[i]*w1[2]; acc[i][7]+=q4[i]*w1[3];
      }
    }
  }
#pragma unroll
  for (int i = 0; i < 4; ++i) {
    int t = t0 + tg * 4 + i;
    f32x4 lo, hi;
#pragma unroll
    for (int jj = 0; jj < 4; ++jj) {
      lo[jj] = acc[i][jj]     + bo[m * 256 + dg * 8 + jj];
      hi[jj] = acc[i][jj + 4] + bo[m * 256 + dg * 8 + 4 + jj];
    }
    float* dst = outp + (size_t)t * 2048 + m * 256 + dg * 8;
    *(f32x4*)(dst)     = lo;
    *(f32x4*)(dst + 4) = hi;
  }
  float lp = 0.0f;
  {
    int ltok = tid & 31, cg2 = tid >> 5;
    const float* xg = XH + (size_t)m * 2097152 + t0 + ltok;
    for (int c = cg2 * 32; c < cg2 * 32 + 32; ++c) {
      float qv = qT[c * 32 + ltok];
      float xv = xg[(size_t)c * 8192];
      float d = qv - xv; lp += d * d;
    }
  }
  red[tid] = (double)lp;
  __syncthreads();
  for (int off = 128; off; off >>= 1) { if (tid < off) red[tid] += red[tid + off]; __syncthreads(); }
  if (tid == 0) lossp[bx] = red[0];
}

// ---------- finalize loss (f32 at outp[16777216]) ----------
__global__ void k_final(const double* __restrict__ lossp, float* __restrict__ outp) {
  __shared__ double red[256];
  int tid = threadIdx.x;
  double s = 0.0;
  for (int i = 0; i < 8; ++i) s += lossp[tid + 256 * i];
  red[tid] = s; __syncthreads();
  for (int off = 128; off; off >>= 1) { if (tid < off) red[tid] += red[tid + off]; __syncthreads(); }
  if (tid == 0) outp[16777216] = (float)(1.25 * red[0] / 16777216.0);
}

// ---------- idx -> f32 ----------
__global__ void k_idxout(const int* __restrict__ idxp, float* __restrict__ outp) {
  int i = blockIdx.x * 256 + threadIdx.x;
  outp[16777217 + i] = (float)idxp[i];
}

extern "C" void kernel_launch(void* const* d_in, const int* in_sizes, int n_in,
                              void* d_out, int out_size, void* d_ws, size_t ws_size,
                              hipStream_t stream) {
  (void)in_sizes; (void)n_in; (void)out_size; (void)ws_size;
  const float* slots = (const float*)d_in[0];
  const float* Wp    = (const float*)d_in[1];
  const float* bp    = (const float*)d_in[2];
  const float* cb    = (const float*)d_in[3];
  const float* Wo    = (const float*)d_in[4];
  const float* bo    = (const float*)d_in[5];
  float* outp = (float*)d_out;
  char* ws = (char*)d_ws;
  double*         lossp = (double*)(ws + WS_LOSSP);
  float*          B32   = (float*)(ws + WS_B32);
  int*            idxp  = (int*)(ws + WS_IDX);
  int*            cnts  = (int*)(ws + WS_CNT);
  unsigned short* lists = (unsigned short*)(ws + WS_LST);
  float*          XH    = (float*)(ws + WS_XH);
  unsigned short* CBTb  = (unsigned short*)(ws + WS_CBT);

  k_cbnormB<<<128,   256, 0, stream>>>(cb, B32);
  k_cbtb   <<<2048,  256, 0, stream>>>(cb, CBTb);
  k_xhat   <<<65536, 256, 0, stream>>>(slots, Wp, bp, XH);
  k_argmin <<<1024,  256, 0, stream>>>(XH, CBTb, B32, cnts, lists);
  k_select <<<1024,  256, 0, stream>>>(XH, cb, B32, cnts, lists, idxp);
  k_out    <<<2048,  256, 0, stream>>>(cb, Wo, bo, XH, idxp, outp, lossp);
  k_final  <<<1,     256, 0, stream>>>(lossp, outp);
  k_idxout <<<256,   256, 0, stream>>>(idxp, outp);
}

// Round 5
// 4030.236 us; speedup vs baseline: 1.8659x; 1.8659x over previous
//
#include <hip/hip_runtime.h>
#include <hip/hip_bf16.h>

typedef float f32x4 __attribute__((ext_vector_type(4)));

// ---- workspace layout (bytes) ----
static constexpr size_t WS_LOSSP = 0;         // double[2048]               -> 16384
static constexpr size_t WS_B32   = 294912;    // float[32768] np-exact B    -> 425984
static constexpr size_t WS_IDX   = 425984;    // int[65536]                 -> 688128
static constexpr size_t WS_CNT   = 688128;    // int[65536] cand counts     -> 950272
static constexpr size_t WS_LST   = 950272;    // ushort[65536*16] cand list -> 3047424
static constexpr size_t WS_XH    = 3145728;   // float[8*256*8192] 64MB     -> 70254592
static constexpr size_t WS_CBT   = 70254592;  // ushort bf16[8*256*4096]    -> 87031808

#define DELTA 3.0e-4f

__device__ inline float b2f(unsigned short u) {
  unsigned int i = ((unsigned int)u) << 16; return __uint_as_float(i);
}
__device__ inline unsigned int fkey(float f) {
  unsigned int b = __float_as_uint(f); return (b & 0x80000000u) ? ~b : (b | 0x80000000u);
}
__device__ inline float funkey(unsigned int u) {
  unsigned int b = (u & 0x80000000u) ? (u ^ 0x80000000u) : ~u; return __uint_as_float(b);
}

// numpy pairwise_sum of 256 SQUARES, AVX512 width-16 emulation:
// n=256 -> split 128+128; each 128 = 8 zmm loads r0..r7,
// combine ((r0+r1)+(r2+r3))+((r4+r5)+(r6+r7)), then GCC _mm512_reduce_add_ps:
// u_i=V_i+V_{8+i}; w_i=u_i+u_{4+i}; (w0+w2)+(w1+w3)
__device__ inline float np_pw256sq(const float* p, int stride) {
#pragma clang fp contract(off)
  float h2[2];
#pragma unroll
  for (int hh = 0; hh < 2; ++hh) {
    const float* q = p + (size_t)(hh * 128) * stride;
    float V[16];
#pragma unroll
    for (int i = 0; i < 16; ++i) {
      float e[8];
#pragma unroll
      for (int j = 0; j < 8; ++j) { float x = q[(size_t)(j * 16 + i) * stride]; e[j] = x * x; }
      float t01 = e[0] + e[1], t23 = e[2] + e[3], t45 = e[4] + e[5], t67 = e[6] + e[7];
      float ta = t01 + t23, tb = t45 + t67;
      V[i] = ta + tb;
    }
    float u[8];
#pragma unroll
    for (int i = 0; i < 8; ++i) u[i] = V[i] + V[8 + i];
    float w[4];
#pragma unroll
    for (int i = 0; i < 4; ++i) w[i] = u[i] + u[4 + i];
    float wa = w[0] + w[2], wb = w[1] + w[3];
    h2[hh] = wa + wb;
  }
  return h2[0] + h2[1];
}

// ---------- np-exact codebook row norms ----------
__global__ __launch_bounds__(256) void k_cbnormB(const float* __restrict__ cb,
                                                 float* __restrict__ B32) {
  int row = blockIdx.x * 256 + threadIdx.x;      // grid 128 -> 32768 rows
  B32[row] = np_pw256sq(cb + (size_t)row * 256, 1);
}

// ---------- transpose codebooks to bf16: CBTb[m][c][k] ----------
__global__ __launch_bounds__(256) void k_cbtb(const float* __restrict__ cb,
                                              unsigned short* __restrict__ cbt) {
  int bx = blockIdx.x;                 // grid 2048 = m(8) * kt(64) * ct(4)
  int ct = bx & 3, kt = (bx >> 2) & 63, m = bx >> 8;
  __shared__ float tile[64][65];
  int tid = threadIdx.x, rr = tid >> 4, cq = tid & 15;
  const float* src = cb + ((size_t)(m * 4096 + kt * 64)) * 256 + ct * 64;
#pragma unroll
  for (int p = 0; p < 4; ++p) {
    int kr = p * 16 + rr;
    f32x4 v = *(const f32x4*)(src + (size_t)kr * 256 + cq * 4);
    tile[kr][cq*4+0]=v[0]; tile[kr][cq*4+1]=v[1]; tile[kr][cq*4+2]=v[2]; tile[kr][cq*4+3]=v[3];
  }
  __syncthreads();
  unsigned short* dst = cbt + ((size_t)(m * 256 + ct * 64)) * 4096 + kt * 64;
#pragma unroll
  for (int p = 0; p < 4; ++p) {
    int cr = p * 16 + rr;
    unsigned int pk[2];
#pragma unroll
    for (int e = 0; e < 2; ++e) {
      __hip_bfloat16 h0 = __float2bfloat16(tile[cq*4 + e*2 + 0][cr]);
      __hip_bfloat16 h1 = __float2bfloat16(tile[cq*4 + e*2 + 1][cr]);
      unsigned int u0 = *reinterpret_cast<unsigned short*>(&h0);
      unsigned int u1 = *reinterpret_cast<unsigned short*>(&h1);
      pk[e] = u0 | (u1 << 16);
    }
    *(uint2*)(dst + (size_t)cr * 4096 + cq * 4) = make_uint2(pk[0], pk[1]);
  }
}

// ---------- x-hat: np.einsum-exact (sequential d, no FMA), stored XH[m][c][t] ----------
// grid 2048 = m(8) * tt(256); each block stages its slots slice ONCE, loops 32 c-groups
__global__ __launch_bounds__(256) void k_xhat(const float* __restrict__ slots,
                                              const float* __restrict__ Wp,
                                              const float* __restrict__ bp,
                                              float* __restrict__ XH) {
#pragma clang fp contract(off)
  int bx = blockIdx.x;
  int m = bx & 7, tt = bx >> 3;
  int t0 = tt * 32;
  __shared__ float Ls[32 * 257];
  __shared__ float Wt[256 * 8];
  int tid = threadIdx.x;
  {
    int r = tid >> 3, q = tid & 7;     // 32 rows x 8 segments of 32 floats
    const float* src = slots + (size_t)(t0 + r) * 2048 + m * 256 + q * 32;
    float* dstrow = &Ls[r * 257 + q * 32];
#pragma unroll
    for (int e = 0; e < 8; ++e) {
      f32x4 v = *(const f32x4*)(src + e * 4);
      dstrow[e*4+0]=v[0]; dstrow[e*4+1]=v[1]; dstrow[e*4+2]=v[2]; dstrow[e*4+3]=v[3];
    }
  }
  int tl = tid & 31, cl = tid >> 5;    // 32 tokens x 8 channels
  const float* lsrow = &Ls[tl * 257];
  for (int cg = 0; cg < 32; ++cg) {
    int c0 = cg * 8;
    __syncthreads();                   // covers Ls staging (first iter) + Wt reuse hazard
    {
      const float* wsrc = Wp + (size_t)m * 65536 + (size_t)tid * 256 + c0;
      f32x4 w0 = *(const f32x4*)(wsrc);
      f32x4 w1 = *(const f32x4*)(wsrc + 4);
      *(f32x4*)&Wt[tid * 8]     = w0;
      *(f32x4*)&Wt[tid * 8 + 4] = w1;
    }
    __syncthreads();
    float acc = 0.0f;
    for (int d = 0; d < 256; ++d) {
      float p = lsrow[d] * Wt[d * 8 + cl];   // separate mul
      acc = acc + p;                          // separate add, strict order
    }
    float xv = acc + bp[m * 256 + c0 + cl];
    XH[(size_t)m * 2097152 + (size_t)(c0 + cl) * 8192 + t0 + tl] = xv;
  }
}

// ---------- fast f32 scan: per-token LDS candidate lists within DELTA of running min ----------
__global__ __launch_bounds__(256) void k_argmin(const float* __restrict__ XH,
                                                const unsigned short* __restrict__ CBTb,
                                                const float* __restrict__ B32,
                                                int* __restrict__ cnts,
                                                unsigned short* __restrict__ lists) {
  int bx = blockIdx.x;                 // grid 1024 = tt(128) * m(8); m=bx&7 -> XCD affinity
  int m = bx & 7, tt = bx >> 3;
  int t0 = tt * 64;
  __shared__ float XT[16384];          // [256 c][64 t] 64KB
  __shared__ float CBc[4096];          // [64 c][64 k] 16KB
  __shared__ unsigned int umin[64];
  __shared__ int lcnt[64];
  __shared__ unsigned short llist[64][16];
  int tid = threadIdx.x;
  const float* xsrc = XH + (size_t)m * 2097152;
#pragma unroll
  for (int i = 0; i < 16; ++i) {
    int f = tid + 256 * i;             // 4096 float4
    int c = f >> 4, to = (f & 15) * 4;
    *(f32x4*)&XT[f * 4] = *(const f32x4*)(xsrc + (size_t)c * 8192 + t0 + to);
  }
  if (tid < 64) { umin[tid] = 0xFFFFFFFFu; lcnt[tid] = 0; }
  int tg = tid & 15, kg = tid >> 4;    // 16 tok-groups x 16 k-groups
  const unsigned short* cbase = CBTb + (size_t)m * 1048576;
  const float* nbase = B32 + m * 4096;

  for (int pass = 0; pass < 2; ++pass) {
    int kchi = (pass == 0) ? 1 : 64;   // pass0: warm-up on kc=0 (min only)
    for (int kc = 0; kc < kchi; ++kc) {
      float acc[4][4] = {};
      for (int c4 = 0; c4 < 4; ++c4) {
        __syncthreads();               // also covers XT staging / umin init on first iter
#pragma unroll
        for (int i = 0; i < 4; ++i) {
          int f = tid + 256 * i;       // 1024 groups of 4 bf16
          int cc = f >> 4, ko = (f & 15) * 4;
          uint2 raw = *(const uint2*)(cbase + (size_t)(c4*64+cc)*4096 + kc*64 + ko);
          CBc[f*4+0] = b2f((unsigned short)(raw.x & 0xFFFF));
          CBc[f*4+1] = b2f((unsigned short)(raw.x >> 16));
          CBc[f*4+2] = b2f((unsigned short)(raw.y & 0xFFFF));
          CBc[f*4+3] = b2f((unsigned short)(raw.y >> 16));
        }
        __syncthreads();
#pragma unroll 8
        for (int c = 0; c < 64; ++c) {
          f32x4 xv = *(const f32x4*)&XT[(c4 * 64 + c) * 64 + tg * 4];
          f32x4 bv = *(const f32x4*)&CBc[c * 64 + kg * 4];
#pragma unroll
          for (int i = 0; i < 4; ++i) {
            acc[i][0] += xv[i]*bv[0]; acc[i][1] += xv[i]*bv[1];
            acc[i][2] += xv[i]*bv[2]; acc[i][3] += xv[i]*bv[3];
          }
        }
      }
      f32x4 cn = *(const f32x4*)(nbase + kc * 64 + kg * 4);
#pragma unroll
      for (int i = 0; i < 4; ++i) {
        int tok = tg * 4 + i;
#pragma unroll
        for (int jj = 0; jj < 4; ++jj) {
          float s = cn[jj] - 2.0f * acc[i][jj];
          unsigned int key = fkey(s);
          if (pass == 0) {
            atomicMin(&umin[tok], key);
          } else {
            unsigned int cur = *((volatile unsigned int*)&umin[tok]);
            float smin = funkey(cur);
            if (s <= smin + DELTA) {   // superset-safe: threshold only ever too loose
              int k = kc * 64 + kg * 4 + jj;
              int pos = atomicAdd(&lcnt[tok], 1);
              if (pos < 16) llist[tok][pos] = (unsigned short)k;
            }
            if (key < cur) atomicMin(&umin[tok], key);
          }
        }
      }
    }
  }
  __syncthreads();
  if (tid < 64) cnts[(t0 + tid) * 8 + m] = lcnt[tid];
  {
    int e = tid;                       // 256 threads copy 1024 entries
#pragma unroll
    for (int r = 0; r < 4; ++r, e += 256) {
      int tok = e >> 4, pos = e & 15;
      lists[((size_t)((t0 + tok) * 8 + m)) * 16 + pos] = llist[tok][pos];
    }
  }
}

// ---------- np-f32-exact final selection among candidates ----------
// overflow (n>16) handled by BLOCK-COOPERATIVE full scan (parallel, not per-quad serial)
__global__ __launch_bounds__(256) void k_select(const float* __restrict__ XH,
                                                const float* __restrict__ cb,
                                                const float* __restrict__ B32,
                                                const int* __restrict__ cnts,
                                                const unsigned short* __restrict__ lists,
                                                int* __restrict__ idxp) {
#pragma clang fp contract(off)
  int bx = blockIdx.x;                 // grid 1024 = tt(128) * m(8)
  int m = bx & 7, tt = bx >> 3;
  int t0 = tt * 64;
  __shared__ float XT2[256 * 65];      // padded [c][t]
  __shared__ float Atok[64];
  __shared__ int ovlist[64];
  __shared__ int ovcnt;
  __shared__ float bvD[64];
  __shared__ int bvK[64];
  int tid = threadIdx.x;
  const float* xsrc = XH + (size_t)m * 2097152;
#pragma unroll
  for (int i = 0; i < 16; ++i) {
    int f = tid + 256 * i;
    int c = f >> 4, to = (f & 15) * 4;
    f32x4 v = *(const f32x4*)(xsrc + (size_t)c * 8192 + t0 + to);
    XT2[c*65+to+0]=v[0]; XT2[c*65+to+1]=v[1]; XT2[c*65+to+2]=v[2]; XT2[c*65+to+3]=v[3];
  }
  if (tid == 0) ovcnt = 0;
  __syncthreads();
  if (tid < 64) Atok[tid] = np_pw256sq(&XT2[tid], 65);   // np.sum(x*x) emulation
  __syncthreads();
  int q = tid >> 2, j = tid & 3;       // 64 quads (token t0+q) x 4 SSE lanes
  const float* cbm = cb + (size_t)m * 1048576;

  // np-exact distance for token column qq, row k; returns same value on all 4 lanes
  auto dist_np = [&](int k, int qq, float A) -> float {
#pragma clang fp contract(off)
    // SSE contig_outstride0_two emulation: one 4-lane accumulator, 2 adds per 8 elems
    const float* row = cbm + (size_t)k * 256;
    float s = 0.0f;
    for (int i8 = 0; i8 < 256; i8 += 8) {
      float p0 = XT2[(i8 + j) * 65 + qq] * row[i8 + j];
      s = s + p0;
      float p1 = XT2[(i8 + 4 + j) * 65 + qq] * row[i8 + 4 + j];
      s = s + p1;
    }
    // numpy SSE horizontal reduce: (s0+s1)+(s2+s3)
    float o  = __shfl_xor(s, 1, 64);
    float ts = s + o;                  // lane j: s_j + s_{j^1}
    float o2 = __shfl_xor(ts, 2, 64);
    float red = ts + o2;               // (s0+s1)+(s2+s3), same value on all 4 lanes
    float T1 = A + B32[m * 4096 + k];  // fl(A + Bk)
    return T1 - 2.0f * red;            // fl(T1 - fl(2E))
  };

  int t8m = (t0 + q) * 8 + m;
  int n = cnts[t8m];
  float A = Atok[q];
  if (n <= 16) {
    float best = __builtin_inff();
    int bk = 0;
    for (int ci = 0; ci < n; ++ci) {
      int k = (int)lists[(size_t)t8m * 16 + ci] & 4095;
      float d2 = dist_np(k, q, A);
      if (d2 < best || (d2 == best && k < bk)) { best = d2; bk = k; }
    }
    if (j == 0) idxp[t8m] = bk;
  } else {
    if (j == 0) { int pos = atomicAdd(&ovcnt, 1); ovlist[pos] = q; }
  }
  __syncthreads();
  int ovn = ovcnt;
  for (int e = 0; e < ovn; ++e) {      // block-cooperative full scan per overflow token
    int qq = ovlist[e];
    float Aq = Atok[qq];
    float bd = __builtin_inff(); int bk2 = 0;
    for (int it = 0; it < 64; ++it) {
      int k = it * 64 + q;             // quad q handles rows {q, 64+q, ...}, ascending
      float d2 = dist_np(k, qq, Aq);
      if (d2 < bd) { bd = d2; bk2 = k; }
    }
    if (j == 0) { bvD[q] = bd; bvK[q] = bk2; }
    __syncthreads();
    if (tid == 0) {
      float bb = bvD[0]; int kk2 = bvK[0];
      for (int r = 1; r < 64; ++r) {
        if (bvD[r] < bb || (bvD[r] == bb && bvK[r] < kk2)) { bb = bvD[r]; kk2 = bvK[r]; }
      }
      idxp[(t0 + qq) * 8 + m] = kk2;
    }
    __syncthreads();
  }
}

// ---------- out = q@Wo + bo (f32), plus per-block loss partials ----------
__global__ __launch_bounds__(256) void k_out(const float* __restrict__ cb,
                                             const float* __restrict__ Wo,
                                             const float* __restrict__ bo,
                                             const float* __restrict__ XH,
                                             const int* __restrict__ idxp,
                                             float* __restrict__ outp,
                                             double* __restrict__ lossp) {
  int bx = blockIdx.x;                 // grid 2048 = tt(256) * m(8)
  int m = bx & 7, tt = bx >> 3;
  int t0 = tt * 32;
  __shared__ float qT[256 * 32];       // [c][t] 32KB
  __shared__ float Wl[64 * 256];       // [c][d] 64KB
  __shared__ double red[256];
  int tid = threadIdx.x;
  {
    int tok = tid & 31, g = tid >> 5;
    int ix = idxp[(size_t)(t0 + tok) * 8 + m] & 4095;   // clamp: no OOB possible
    const float* qrow = cb + ((size_t)m * 4096 + ix) * 256;
#pragma unroll
    for (int i = 0; i < 8; ++i) {
      int c = (g * 8 + i) * 4;
      f32x4 v = *(const f32x4*)(qrow + c);
      qT[(c+0)*32+tok]=v[0]; qT[(c+1)*32+tok]=v[1]; qT[(c+2)*32+tok]=v[2]; qT[(c+3)*32+tok]=v[3];
    }
  }
  int tg = tid & 7, dg = tid >> 3;     // 8 tok-groups(4 tok) x 32 d-groups(8 d)
  float acc[4][8] = {};
  const float* wbase = Wo + (size_t)m * 65536;
  for (int c4 = 0; c4 < 4; ++c4) {
    __syncthreads();
#pragma unroll
    for (int i = 0; i < 16; ++i) {
      int f = tid + 256 * i;
      int cr = f >> 6, doff = (f & 63) * 4;
      *(f32x4*)&Wl[f * 4] = *(const f32x4*)(wbase + (size_t)(c4 * 64 + cr) * 256 + doff);
    }
    __syncthreads();
#pragma unroll 4
    for (int c = 0; c < 64; ++c) {
      f32x4 q4 = *(const f32x4*)&qT[(c4 * 64 + c) * 32 + tg * 4];
      f32x4 w0 = *(const f32x4*)&Wl[c * 256 + dg * 8];
      f32x4 w1 = *(const f32x4*)&Wl[c * 256 + dg * 8 + 4];
#pragma unroll
      for (int i = 0; i < 4; ++i) {
        acc[i][0]+=q4[i]*w0[0]; acc[i][1]+=q4[i]*w0[1]; acc[i][2]+=q4[i]*w0[2]; acc[i][3]+=q4[i]*w0[3];
        acc[i][4]+=q4[i]*w1[0]; acc[i][5]+=q4[i]*w1[1]; acc[i][6]+=q4[i]*w1[2]; acc[i][7]+=q4[i]*w1[3];
      }
    }
  }
#pragma unroll
  for (int i = 0; i < 4; ++i) {
    int t = t0 + tg * 4 + i;
    f32x4 lo, hi;
#pragma unroll
    for (int jj = 0; jj < 4; ++jj) {
      lo[jj] = acc[i][jj]     + bo[m * 256 + dg * 8 + jj];
      hi[jj] = acc[i][jj + 4] + bo[m * 256 + dg * 8 + 4 + jj];
    }
    float* dst = outp + (size_t)t * 2048 + m * 256 + dg * 8;
    *(f32x4*)(dst)     = lo;
    *(f32x4*)(dst + 4) = hi;
  }
  float lp = 0.0f;
  {
    int ltok = tid & 31, cg2 = tid >> 5;
    const float* xg = XH + (size_t)m * 2097152 + t0 + ltok;
    for (int c = cg2 * 32; c < cg2 * 32 + 32; ++c) {
      float qv = qT[c * 32 + ltok];
      float xv = xg[(size_t)c * 8192];
      float d = qv - xv; lp += d * d;
    }
  }
  red[tid] = (double)lp;
  __syncthreads();
  for (int off = 128; off; off >>= 1) { if (tid < off) red[tid] += red[tid + off]; __syncthreads(); }
  if (tid == 0) lossp[bx] = red[0];
}

// ---------- finalize loss (f32 at outp[16777216]) ----------
__global__ void k_final(const double* __restrict__ lossp, float* __restrict__ outp) {
  __shared__ double red[256];
  int tid = threadIdx.x;
  double s = 0.0;
  for (int i = 0; i < 8; ++i) s += lossp[tid + 256 * i];
  red[tid] = s; __syncthreads();
  for (int off = 128; off; off >>= 1) { if (tid < off) red[tid] += red[tid + off]; __syncthreads(); }
  if (tid == 0) outp[16777216] = (float)(1.25 * red[0] / 16777216.0);
}

// ---------- idx -> f32 ----------
__global__ void k_idxout(const int* __restrict__ idxp, float* __restrict__ outp) {
  int i = blockIdx.x * 256 + threadIdx.x;
  outp[16777217 + i] = (float)idxp[i];
}

extern "C" void kernel_launch(void* const* d_in, const int* in_sizes, int n_in,
                              void* d_out, int out_size, void* d_ws, size_t ws_size,
                              hipStream_t stream) {
  (void)in_sizes; (void)n_in; (void)out_size; (void)ws_size;
  const float* slots = (const float*)d_in[0];
  const float* Wp    = (const float*)d_in[1];
  const float* bp    = (const float*)d_in[2];
  const float* cb    = (const float*)d_in[3];
  const float* Wo    = (const float*)d_in[4];
  const float* bo    = (const float*)d_in[5];
  float* outp = (float*)d_out;
  char* ws = (char*)d_ws;
  double*         lossp = (double*)(ws + WS_LOSSP);
  float*          B32   = (float*)(ws + WS_B32);
  int*            idxp  = (int*)(ws + WS_IDX);
  int*            cnts  = (int*)(ws + WS_CNT);
  unsigned short* lists = (unsigned short*)(ws + WS_LST);
  float*          XH    = (float*)(ws + WS_XH);
  unsigned short* CBTb  = (unsigned short*)(ws + WS_CBT);

  k_cbnormB<<<128,   256, 0, stream>>>(cb, B32);
  k_cbtb   <<<2048,  256, 0, stream>>>(cb, CBTb);
  k_xhat   <<<2048,  256, 0, stream>>>(slots, Wp, bp, XH);
  k_argmin <<<1024,  256, 0, stream>>>(XH, CBTb, B32, cnts, lists);
  k_select <<<1024,  256, 0, stream>>>(XH, cb, B32, cnts, lists, idxp);
  k_out    <<<2048,  256, 0, stream>>>(cb, Wo, bo, XH, idxp, outp, lossp);
  k_final  <<<1,     256, 0, stream>>>(lossp, outp);
  k_idxout <<<256,   256, 0, stream>>>(idxp, outp);
}

// Round 6
// 3944.946 us; speedup vs baseline: 1.9062x; 1.0216x over previous
//
#include <hip/hip_runtime.h>
#include <hip/hip_bf16.h>

typedef float f32x4 __attribute__((ext_vector_type(4)));
typedef short bf16x8 __attribute__((ext_vector_type(8)));

// ---- workspace layout (bytes) ----
static constexpr size_t WS_LOSSP = 0;         // double[2048]               -> 16384
static constexpr size_t WS_B32   = 294912;    // float[32768] np-exact B    -> 425984
static constexpr size_t WS_IDX   = 425984;    // int[65536]                 -> 688128
static constexpr size_t WS_CNT   = 688128;    // int[65536] cand counts     -> 950272
static constexpr size_t WS_LST   = 950272;    // ushort[65536*16] cand list -> 3047424
static constexpr size_t WS_XH    = 3145728;   // float[8*256*8192] 64MB     -> 70254592
static constexpr size_t WS_CBT   = 70254592;  // ushort bf16[8][4096][256]  -> 87031808

#define DELTA 3.0e-4f

__device__ inline float b2f(unsigned short u) {
  unsigned int i = ((unsigned int)u) << 16; return __uint_as_float(i);
}
__device__ inline unsigned int fkey(float f) {
  unsigned int b = __float_as_uint(f); return (b & 0x80000000u) ? ~b : (b | 0x80000000u);
}
__device__ inline float funkey(unsigned int u) {
  unsigned int b = (u & 0x80000000u) ? (u ^ 0x80000000u) : ~u; return __uint_as_float(b);
}

// numpy pairwise_sum of 256 SQUARES, AVX512 width-16 emulation
__device__ inline float np_pw256sq(const float* p, int stride) {
#pragma clang fp contract(off)
  float h2[2];
#pragma unroll
  for (int hh = 0; hh < 2; ++hh) {
    const float* q = p + (size_t)(hh * 128) * stride;
    float V[16];
#pragma unroll
    for (int i = 0; i < 16; ++i) {
      float e[8];
#pragma unroll
      for (int j = 0; j < 8; ++j) { float x = q[(size_t)(j * 16 + i) * stride]; e[j] = x * x; }
      float t01 = e[0] + e[1], t23 = e[2] + e[3], t45 = e[4] + e[5], t67 = e[6] + e[7];
      float ta = t01 + t23, tb = t45 + t67;
      V[i] = ta + tb;
    }
    float u[8];
#pragma unroll
    for (int i = 0; i < 8; ++i) u[i] = V[i] + V[8 + i];
    float w[4];
#pragma unroll
    for (int i = 0; i < 4; ++i) w[i] = u[i] + u[4 + i];
    float wa = w[0] + w[2], wb = w[1] + w[3];
    h2[hh] = wa + wb;
  }
  return h2[0] + h2[1];
}

// ---------- np-exact codebook row norms ----------
__global__ __launch_bounds__(256) void k_cbnormB(const float* __restrict__ cb,
                                                 float* __restrict__ B32) {
  int row = blockIdx.x * 256 + threadIdx.x;      // grid 128 -> 32768 rows
  B32[row] = np_pw256sq(cb + (size_t)row * 256, 1);
}

// ---------- bf16 compress codebooks (layout preserved: [m][k][c]) ----------
__global__ __launch_bounds__(256) void k_cbb(const float* __restrict__ cb,
                                             unsigned short* __restrict__ cbb) {
  size_t i = ((size_t)blockIdx.x * 256 + threadIdx.x) * 8;   // grid 4096 -> 8.39M elems
  f32x4 v0 = *(const f32x4*)(cb + i);
  f32x4 v1 = *(const f32x4*)(cb + i + 4);
  union { unsigned short s[8]; uint4 u; } o;
#pragma unroll
  for (int j = 0; j < 4; ++j) {
    __hip_bfloat16 h0 = __float2bfloat16(v0[j]);
    __hip_bfloat16 h1 = __float2bfloat16(v1[j]);
    o.s[j]     = *reinterpret_cast<unsigned short*>(&h0);
    o.s[4 + j] = *reinterpret_cast<unsigned short*>(&h1);
  }
  *(uint4*)(cbb + i) = o.u;
}

// ---------- x-hat: np.einsum-exact (sequential d, no FMA), stored XH[m][c][t] ----------
__global__ __launch_bounds__(256) void k_xhat(const float* __restrict__ slots,
                                              const float* __restrict__ Wp,
                                              const float* __restrict__ bp,
                                              float* __restrict__ XH) {
#pragma clang fp contract(off)
  int bx = blockIdx.x;                 // grid 2048 = m(8) * tt(256)
  int m = bx & 7, tt = bx >> 3;
  int t0 = tt * 32;
  __shared__ float Ls[32 * 257];
  __shared__ float Wt[256 * 8];
  int tid = threadIdx.x;
  {
    int r = tid >> 3, q = tid & 7;     // 32 rows x 8 segments of 32 floats
    const float* src = slots + (size_t)(t0 + r) * 2048 + m * 256 + q * 32;
    float* dstrow = &Ls[r * 257 + q * 32];
#pragma unroll
    for (int e = 0; e < 8; ++e) {
      f32x4 v = *(const f32x4*)(src + e * 4);
      dstrow[e*4+0]=v[0]; dstrow[e*4+1]=v[1]; dstrow[e*4+2]=v[2]; dstrow[e*4+3]=v[3];
    }
  }
  int tl = tid & 31, cl = tid >> 5;    // 32 tokens x 8 channels
  const float* lsrow = &Ls[tl * 257];
  for (int cg = 0; cg < 32; ++cg) {
    int c0 = cg * 8;
    __syncthreads();                   // covers Ls staging (first iter) + Wt reuse hazard
    {
      const float* wsrc = Wp + (size_t)m * 65536 + (size_t)tid * 256 + c0;
      f32x4 w0 = *(const f32x4*)(wsrc);
      f32x4 w1 = *(const f32x4*)(wsrc + 4);
      *(f32x4*)&Wt[tid * 8]     = w0;
      *(f32x4*)&Wt[tid * 8 + 4] = w1;
    }
    __syncthreads();
    float acc = 0.0f;
    for (int d = 0; d < 256; ++d) {
      float p = lsrow[d] * Wt[d * 8 + cl];   // separate mul
      acc = acc + p;                          // separate add, strict order
    }
    float xv = acc + bp[m * 256 + c0 + cl];
    XH[(size_t)m * 2097152 + (size_t)(c0 + cl) * 8192 + t0 + tl] = xv;
  }
}

// ---------- MFMA bf16 scan: running min + candidates within DELTA ----------
// grid 512 = tt(64) * m(8); block = 4 waves, wave = 32 toks (2 MFMA row-tiles)
__global__ __launch_bounds__(256) void k_argmin(const float* __restrict__ XH,
                                                const unsigned short* __restrict__ CBb,
                                                const float* __restrict__ B32,
                                                int* __restrict__ cnts,
                                                unsigned short* __restrict__ lists) {
  int bx = blockIdx.x;
  int m = bx & 7, tt = bx >> 3;
  int t0 = tt * 128;
  __shared__ float Bs[4096];           // B32[m] staged (16KB)
  __shared__ unsigned int umin[128];
  __shared__ int lcnt[128];
  __shared__ unsigned short llist[128][16];
  int tid = threadIdx.x;
  {
    const f32x4* src = (const f32x4*)(B32 + m * 4096);
    f32x4* dst = (f32x4*)Bs;
#pragma unroll
    for (int i = 0; i < 4; ++i) dst[tid + 256 * i] = src[tid + 256 * i];
  }
  if (tid < 128) { umin[tid] = 0xFFFFFFFFu; lcnt[tid] = 0; }
  int w = tid >> 6, l = tid & 63;
  int row = l & 15, grp = l >> 4;      // A/B fragment row (=tok for A, =k for B); c-group
  const float FINF = __builtin_inff();

  // block-local token slots for this lane's accumulator rows (D: tok=(grp*4+r), a-tile offset)
  int tloc[8];
#pragma unroll
  for (int r = 0; r < 4; ++r) {
    tloc[r]     = w * 32 + grp * 4 + r;        // a=0
    tloc[4 + r] = w * 32 + 16 + grp * 4 + r;   // a=1
  }

  // A-fragments: lane l holds X[tok = base + (l&15)][c = cs*32 + grp*8 + j], bf16
  bf16x8 afrag0[8], afrag1[8];
  {
    const float* xbase = XH + (size_t)m * 2097152;   // [c][t]
#pragma unroll
    for (int cs = 0; cs < 8; ++cs) {
      union { short s[8]; bf16x8 v; } u0, u1;
#pragma unroll
      for (int j = 0; j < 8; ++j) {
        int c = cs * 32 + grp * 8 + j;
        float x0 = xbase[(size_t)c * 8192 + t0 + w * 32 + row];
        float x1 = xbase[(size_t)c * 8192 + t0 + w * 32 + 16 + row];
        __hip_bfloat16 h0 = __float2bfloat16(x0);
        __hip_bfloat16 h1 = __float2bfloat16(x1);
        u0.s[j] = *reinterpret_cast<short*>(&h0);
        u1.s[j] = *reinterpret_cast<short*>(&h1);
      }
      afrag0[cs] = u0.v; afrag1[cs] = u1.v;
    }
  }
  __syncthreads();                     // Bs + umin/lcnt ready

  const unsigned short* cbbase = CBb + (size_t)m * 1048576 + (size_t)row * 256 + grp * 8;
  float rmin[8], treg[8];
#pragma unroll
  for (int sl = 0; sl < 8; ++sl) { rmin[sl] = FINF; treg[sl] = FINF; }

  auto load_b = [&](int kt, bf16x8* bf) {
    const unsigned short* p = cbbase + (size_t)kt * 4096;
#pragma unroll
    for (int cs = 0; cs < 8; ++cs) bf[cs] = *(const bf16x8*)(p + cs * 32);
  };
  auto mfma_tile = [&](const bf16x8* bf, f32x4& a0, f32x4& a1) {
    a0 = f32x4{0.f,0.f,0.f,0.f}; a1 = f32x4{0.f,0.f,0.f,0.f};
#pragma unroll
    for (int cs = 0; cs < 8; ++cs) {
      a0 = __builtin_amdgcn_mfma_f32_16x16x32_bf16(afrag0[cs], bf[cs], a0, 0, 0, 0);
      a1 = __builtin_amdgcn_mfma_f32_16x16x32_bf16(afrag1[cs], bf[cs], a1, 0, 0, 0);
    }
  };

  bf16x8 bcur[8], bnxt[8];
  // ---- warm-up: k-tiles 0..3 (64 k), min only ----
  for (int kt = 0; kt < 4; ++kt) {
    load_b(kt, bcur);
    f32x4 a0, a1; mfma_tile(bcur, a0, a1);
    float Bv = Bs[kt * 16 + row];
#pragma unroll
    for (int r = 0; r < 4; ++r) {
      rmin[r]     = fminf(rmin[r],     fmaf(-2.0f, a0[r], Bv));
      rmin[4 + r] = fminf(rmin[4 + r], fmaf(-2.0f, a1[r], Bv));
    }
  }
#pragma unroll
  for (int sl = 0; sl < 8; ++sl) atomicMin(&umin[tloc[sl]], fkey(rmin[sl]));
  __syncthreads();
#pragma unroll
  for (int sl = 0; sl < 8; ++sl) treg[sl] = funkey(umin[tloc[sl]]);

  // ---- main pass: all 256 k-tiles, with candidate inserts ----
  auto process = [&](int kt, const bf16x8* bf) {
    f32x4 a0, a1; mfma_tile(bf, a0, a1);
    float Bv = Bs[kt * 16 + row];
    int k = (kt << 4) + row;
#pragma unroll
    for (int r = 0; r < 4; ++r) {
      float s0 = fmaf(-2.0f, a0[r], Bv);
      float s1 = fmaf(-2.0f, a1[r], Bv);
      if (s0 <= fminf(treg[r], rmin[r]) + DELTA) {
        int pos = atomicAdd(&lcnt[tloc[r]], 1);
        if (pos < 16) llist[tloc[r]][pos] = (unsigned short)k;
      }
      rmin[r] = fminf(rmin[r], s0);
      if (s1 <= fminf(treg[4 + r], rmin[4 + r]) + DELTA) {
        int pos = atomicAdd(&lcnt[tloc[4 + r]], 1);
        if (pos < 16) llist[tloc[4 + r]][pos] = (unsigned short)k;
      }
      rmin[4 + r] = fminf(rmin[4 + r], s1);
    }
    if ((kt & 15) == 15) {             // periodic global-min merge (stale-safe superset)
#pragma unroll
      for (int sl = 0; sl < 8; ++sl) {
        atomicMin(&umin[tloc[sl]], fkey(rmin[sl]));
        treg[sl] = funkey(*(volatile unsigned int*)&umin[tloc[sl]]);
      }
    }
  };

  load_b(0, bcur);
  for (int kt = 0; kt < 256; kt += 2) {
    load_b(kt + 1, bnxt);
    process(kt, bcur);
    if (kt + 2 < 256) load_b(kt + 2, bcur);
    process(kt + 1, bnxt);
  }

  __syncthreads();
  if (tid < 128) cnts[(size_t)(t0 + tid) * 8 + m] = lcnt[tid];
  {
    int e = tid;                       // 256 threads copy 2048 entries
#pragma unroll
    for (int rr = 0; rr < 8; ++rr, e += 256) {
      int tok = e >> 4, pos = e & 15;
      lists[((size_t)((t0 + tok) * 8 + m)) * 16 + pos] = llist[tok][pos];
    }
  }
}

// ---------- np-f32-exact final selection among candidates ----------
__global__ __launch_bounds__(256) void k_select(const float* __restrict__ XH,
                                                const float* __restrict__ cb,
                                                const float* __restrict__ B32,
                                                const int* __restrict__ cnts,
                                                const unsigned short* __restrict__ lists,
                                                int* __restrict__ idxp) {
#pragma clang fp contract(off)
  int bx = blockIdx.x;                 // grid 1024 = tt(128) * m(8)
  int m = bx & 7, tt = bx >> 3;
  int t0 = tt * 64;
  __shared__ float XT2[256 * 65];      // padded [c][t]
  __shared__ float Atok[64];
  __shared__ int ovlist[64];
  __shared__ int ovcnt;
  __shared__ float bvD[64];
  __shared__ int bvK[64];
  int tid = threadIdx.x;
  const float* xsrc = XH + (size_t)m * 2097152;
#pragma unroll
  for (int i = 0; i < 16; ++i) {
    int f = tid + 256 * i;
    int c = f >> 4, to = (f & 15) * 4;
    f32x4 v = *(const f32x4*)(xsrc + (size_t)c * 8192 + t0 + to);
    XT2[c*65+to+0]=v[0]; XT2[c*65+to+1]=v[1]; XT2[c*65+to+2]=v[2]; XT2[c*65+to+3]=v[3];
  }
  if (tid == 0) ovcnt = 0;
  __syncthreads();
  if (tid < 64) Atok[tid] = np_pw256sq(&XT2[tid], 65);   // np.sum(x*x) emulation
  __syncthreads();
  int q = tid >> 2, j = tid & 3;       // 64 quads (token t0+q) x 4 SSE lanes
  const float* cbm = cb + (size_t)m * 1048576;

  auto dist_np = [&](int k, int qq, float A) -> float {
#pragma clang fp contract(off)
    const float* row = cbm + (size_t)k * 256;
    float s = 0.0f;
    for (int i8 = 0; i8 < 256; i8 += 8) {
      float p0 = XT2[(i8 + j) * 65 + qq] * row[i8 + j];
      s = s + p0;
      float p1 = XT2[(i8 + 4 + j) * 65 + qq] * row[i8 + 4 + j];
      s = s + p1;
    }
    float o  = __shfl_xor(s, 1, 64);
    float ts = s + o;
    float o2 = __shfl_xor(ts, 2, 64);
    float red = ts + o2;               // (s0+s1)+(s2+s3)
    float T1 = A + B32[m * 4096 + k];  // fl(A + Bk)
    return T1 - 2.0f * red;            // fl(T1 - fl(2E))
  };

  int t8m = (t0 + q) * 8 + m;
  int n = cnts[t8m];
  float A = Atok[q];
  if (n <= 16) {
    float best = __builtin_inff();
    int bk = 0;
    for (int ci = 0; ci < n; ++ci) {
      int k = (int)lists[(size_t)t8m * 16 + ci] & 4095;
      float d2 = dist_np(k, q, A);
      if (d2 < best || (d2 == best && k < bk)) { best = d2; bk = k; }
    }
    if (j == 0) idxp[t8m] = bk;
  } else {
    if (j == 0) { int pos = atomicAdd(&ovcnt, 1); ovlist[pos] = q; }
  }
  __syncthreads();
  int ovn = ovcnt;
  for (int e = 0; e < ovn; ++e) {      // block-cooperative full scan per overflow token
    int qq = ovlist[e];
    float Aq = Atok[qq];
    float bd = __builtin_inff(); int bk2 = 0;
    for (int it = 0; it < 64; ++it) {
      int k = it * 64 + q;
      float d2 = dist_np(k, qq, Aq);
      if (d2 < bd) { bd = d2; bk2 = k; }
    }
    if (j == 0) { bvD[q] = bd; bvK[q] = bk2; }
    __syncthreads();
    if (tid == 0) {
      float bb = bvD[0]; int kk2 = bvK[0];
      for (int r = 1; r < 64; ++r) {
        if (bvD[r] < bb || (bvD[r] == bb && bvK[r] < kk2)) { bb = bvD[r]; kk2 = bvK[r]; }
      }
      idxp[(t0 + qq) * 8 + m] = kk2;
    }
    __syncthreads();
  }
}

// ---------- out = q@Wo + bo (f32), plus per-block loss partials ----------
__global__ __launch_bounds__(256) void k_out(const float* __restrict__ cb,
                                             const float* __restrict__ Wo,
                                             const float* __restrict__ bo,
                                             const float* __restrict__ XH,
                                             const int* __restrict__ idxp,
                                             float* __restrict__ outp,
                                             double* __restrict__ lossp) {
  int bx = blockIdx.x;                 // grid 2048 = tt(256) * m(8)
  int m = bx & 7, tt = bx >> 3;
  int t0 = tt * 32;
  __shared__ float qT[256 * 32];       // [c][t] 32KB
  __shared__ float Wl[64 * 256];       // [c][d] 64KB
  __shared__ double red[256];
  int tid = threadIdx.x;
  {
    int tok = tid & 31, g = tid >> 5;
    int ix = idxp[(size_t)(t0 + tok) * 8 + m] & 4095;
    const float* qrow = cb + ((size_t)m * 4096 + ix) * 256;
#pragma unroll
    for (int i = 0; i < 8; ++i) {
      int c = (g * 8 + i) * 4;
      f32x4 v = *(const f32x4*)(qrow + c);
      qT[(c+0)*32+tok]=v[0]; qT[(c+1)*32+tok]=v[1]; qT[(c+2)*32+tok]=v[2]; qT[(c+3)*32+tok]=v[3];
    }
  }
  int tg = tid & 7, dg = tid >> 3;     // 8 tok-groups(4 tok) x 32 d-groups(8 d)
  float acc[4][8] = {};
  const float* wbase = Wo + (size_t)m * 65536;
  for (int c4 = 0; c4 < 4; ++c4) {
    __syncthreads();
#pragma unroll
    for (int i = 0; i < 16; ++i) {
      int f = tid + 256 * i;
      int cr = f >> 6, doff = (f & 63) * 4;
      *(f32x4*)&Wl[f * 4] = *(const f32x4*)(wbase + (size_t)(c4 * 64 + cr) * 256 + doff);
    }
    __syncthreads();
#pragma unroll 4
    for (int c = 0; c < 64; ++c) {
      f32x4 q4 = *(const f32x4*)&qT[(c4 * 64 + c) * 32 + tg * 4];
      f32x4 w0 = *(const f32x4*)&Wl[c * 256 + dg * 8];
      f32x4 w1 = *(const f32x4*)&Wl[c * 256 + dg * 8 + 4];
#pragma unroll
      for (int i = 0; i < 4; ++i) {
        acc[i][0]+=q4[i]*w0[0]; acc[i][1]+=q4[i]*w0[1]; acc[i][2]+=q4[i]*w0[2]; acc[i][3]+=q4[i]*w0[3];
        acc[i][4]+=q4[i]*w1[0]; acc[i][5]+=q4[i]*w1[1]; acc[i][6]+=q4[i]*w1[2]; acc[i][7]+=q4[i]*w1[3];
      }
    }
  }
#pragma unroll
  for (int i = 0; i < 4; ++i) {
    int t = t0 + tg * 4 + i;
    f32x4 lo, hi;
#pragma unroll
    for (int jj = 0; jj < 4; ++jj) {
      lo[jj] = acc[i][jj]     + bo[m * 256 + dg * 8 + jj];
      hi[jj] = acc[i][jj + 4] + bo[m * 256 + dg * 8 + 4 + jj];
    }
    float* dst = outp + (size_t)t * 2048 + m * 256 + dg * 8;
    *(f32x4*)(dst)     = lo;
    *(f32x4*)(dst + 4) = hi;
  }
  float lp = 0.0f;
  {
    int ltok = tid & 31, cg2 = tid >> 5;
    const float* xg = XH + (size_t)m * 2097152 + t0 + ltok;
    for (int c = cg2 * 32; c < cg2 * 32 + 32; ++c) {
      float qv = qT[c * 32 + ltok];
      float xv = xg[(size_t)c * 8192];
      float d = qv - xv; lp += d * d;
    }
  }
  red[tid] = (double)lp;
  __syncthreads();
  for (int off = 128; off; off >>= 1) { if (tid < off) red[tid] += red[tid + off]; __syncthreads(); }
  if (tid == 0) lossp[bx] = red[0];
}

// ---------- finalize loss (f32 at outp[16777216]) ----------
__global__ void k_final(const double* __restrict__ lossp, float* __restrict__ outp) {
  __shared__ double red[256];
  int tid = threadIdx.x;
  double s = 0.0;
  for (int i = 0; i < 8; ++i) s += lossp[tid + 256 * i];
  red[tid] = s; __syncthreads();
  for (int off = 128; off; off >>= 1) { if (tid < off) red[tid] += red[tid + off]; __syncthreads(); }
  if (tid == 0) outp[16777216] = (float)(1.25 * red[0] / 16777216.0);
}

// ---------- idx -> f32 ----------
__global__ void k_idxout(const int* __restrict__ idxp, float* __restrict__ outp) {
  int i = blockIdx.x * 256 + threadIdx.x;
  outp[16777217 + i] = (float)idxp[i];
}

extern "C" void kernel_launch(void* const* d_in, const int* in_sizes, int n_in,
                              void* d_out, int out_size, void* d_ws, size_t ws_size,
                              hipStream_t stream) {
  (void)in_sizes; (void)n_in; (void)out_size; (void)ws_size;
  const float* slots = (const float*)d_in[0];
  const float* Wp    = (const float*)d_in[1];
  const float* bp    = (const float*)d_in[2];
  const float* cb    = (const float*)d_in[3];
  const float* Wo    = (const float*)d_in[4];
  const float* bo    = (const float*)d_in[5];
  float* outp = (float*)d_out;
  char* ws = (char*)d_ws;
  double*         lossp = (double*)(ws + WS_LOSSP);
  float*          B32   = (float*)(ws + WS_B32);
  int*            idxp  = (int*)(ws + WS_IDX);
  int*            cnts  = (int*)(ws + WS_CNT);
  unsigned short* lists = (unsigned short*)(ws + WS_LST);
  float*          XH    = (float*)(ws + WS_XH);
  unsigned short* CBb   = (unsigned short*)(ws + WS_CBT);

  k_cbnormB<<<128,  256, 0, stream>>>(cb, B32);
  k_cbb    <<<4096, 256, 0, stream>>>(cb, CBb);
  k_xhat   <<<2048, 256, 0, stream>>>(slots, Wp, bp, XH);
  k_argmin <<<512,  256, 0, stream>>>(XH, CBb, B32, cnts, lists);
  k_select <<<1024, 256, 0, stream>>>(XH, cb, B32, cnts, lists, idxp);
  k_out    <<<2048, 256, 0, stream>>>(cb, Wo, bo, XH, idxp, outp, lossp);
  k_final  <<<1,    256, 0, stream>>>(lossp, outp);
  k_idxout <<<256,  256, 0, stream>>>(idxp, outp);
}

// Round 7
// 1644.569 us; speedup vs baseline: 4.5727x; 2.3988x over previous
//
#include <hip/hip_runtime.h>
#include <hip/hip_bf16.h>

typedef float f32x4 __attribute__((ext_vector_type(4)));
typedef short bf16x8 __attribute__((ext_vector_type(8)));

// ---- workspace layout (bytes) ----
static constexpr size_t WS_LOSSP = 0;         // double[2048]               -> 16384
static constexpr size_t WS_B32   = 294912;    // float[32768] np-exact B    -> 425984
static constexpr size_t WS_IDX   = 425984;    // int[65536]                 -> 688128
static constexpr size_t WS_CNT   = 688128;    // int[65536] cand counts     -> 950272
static constexpr size_t WS_LST   = 950272;    // ushort[65536*16] cand list -> 3047424
static constexpr size_t WS_XH    = 3145728;   // float[8*256*8192] 64MB     -> 70254592
static constexpr size_t WS_CBT   = 70254592;  // ushort bf16[8][4096][256]  -> 87031808

#define DELTA 3.0e-4f

__device__ inline float b2f(unsigned short u) {
  unsigned int i = ((unsigned int)u) << 16; return __uint_as_float(i);
}
__device__ inline unsigned int fkey(float f) {
  unsigned int b = __float_as_uint(f); return (b & 0x80000000u) ? ~b : (b | 0x80000000u);
}
__device__ inline float funkey(unsigned int u) {
  unsigned int b = (u & 0x80000000u) ? (u ^ 0x80000000u) : ~u; return __uint_as_float(b);
}

// numpy pairwise_sum of 256 SQUARES, AVX512 width-16 emulation
__device__ inline float np_pw256sq(const float* p, int stride) {
#pragma clang fp contract(off)
  float h2[2];
#pragma unroll
  for (int hh = 0; hh < 2; ++hh) {
    const float* q = p + (size_t)(hh * 128) * stride;
    float V[16];
#pragma unroll
    for (int i = 0; i < 16; ++i) {
      float e[8];
#pragma unroll
      for (int j = 0; j < 8; ++j) { float x = q[(size_t)(j * 16 + i) * stride]; e[j] = x * x; }
      float t01 = e[0] + e[1], t23 = e[2] + e[3], t45 = e[4] + e[5], t67 = e[6] + e[7];
      float ta = t01 + t23, tb = t45 + t67;
      V[i] = ta + tb;
    }
    float u[8];
#pragma unroll
    for (int i = 0; i < 8; ++i) u[i] = V[i] + V[8 + i];
    float w[4];
#pragma unroll
    for (int i = 0; i < 4; ++i) w[i] = u[i] + u[4 + i];
    float wa = w[0] + w[2], wb = w[1] + w[3];
    h2[hh] = wa + wb;
  }
  return h2[0] + h2[1];
}

// ---------- np-exact codebook row norms ----------
__global__ __launch_bounds__(256) void k_cbnormB(const float* __restrict__ cb,
                                                 float* __restrict__ B32) {
  int row = blockIdx.x * 256 + threadIdx.x;      // grid 128 -> 32768 rows
  B32[row] = np_pw256sq(cb + (size_t)row * 256, 1);
}

// ---------- bf16 compress codebooks (layout preserved: [m][k][c]) ----------
__global__ __launch_bounds__(256) void k_cbb(const float* __restrict__ cb,
                                             unsigned short* __restrict__ cbb) {
  size_t i = ((size_t)blockIdx.x * 256 + threadIdx.x) * 8;   // grid 4096 -> 8.39M elems
  f32x4 v0 = *(const f32x4*)(cb + i);
  f32x4 v1 = *(const f32x4*)(cb + i + 4);
  union { unsigned short s[8]; uint4 u; } o;
#pragma unroll
  for (int j = 0; j < 4; ++j) {
    __hip_bfloat16 h0 = __float2bfloat16(v0[j]);
    __hip_bfloat16 h1 = __float2bfloat16(v1[j]);
    o.s[j]     = *reinterpret_cast<unsigned short*>(&h0);
    o.s[4 + j] = *reinterpret_cast<unsigned short*>(&h1);
  }
  *(uint4*)(cbb + i) = o.u;
}

// ---------- x-hat: np.einsum-exact (sequential d, no FMA), stored XH[m][c][t] ----------
__global__ __launch_bounds__(256) void k_xhat(const float* __restrict__ slots,
                                              const float* __restrict__ Wp,
                                              const float* __restrict__ bp,
                                              float* __restrict__ XH) {
#pragma clang fp contract(off)
  int bx = blockIdx.x;                 // grid 2048 = m(8) * tt(256)
  int m = bx & 7, tt = bx >> 3;
  int t0 = tt * 32;
  __shared__ float Ls[32 * 257];
  __shared__ float Wt[256 * 8];
  int tid = threadIdx.x;
  {
    int r = tid >> 3, q = tid & 7;     // 32 rows x 8 segments of 32 floats
    const float* src = slots + (size_t)(t0 + r) * 2048 + m * 256 + q * 32;
    float* dstrow = &Ls[r * 257 + q * 32];
#pragma unroll
    for (int e = 0; e < 8; ++e) {
      f32x4 v = *(const f32x4*)(src + e * 4);
      dstrow[e*4+0]=v[0]; dstrow[e*4+1]=v[1]; dstrow[e*4+2]=v[2]; dstrow[e*4+3]=v[3];
    }
  }
  int tl = tid & 31, cl = tid >> 5;    // 32 tokens x 8 channels
  const float* lsrow = &Ls[tl * 257];
  for (int cg = 0; cg < 32; ++cg) {
    int c0 = cg * 8;
    __syncthreads();                   // covers Ls staging (first iter) + Wt reuse hazard
    {
      const float* wsrc = Wp + (size_t)m * 65536 + (size_t)tid * 256 + c0;
      f32x4 w0 = *(const f32x4*)(wsrc);
      f32x4 w1 = *(const f32x4*)(wsrc + 4);
      *(f32x4*)&Wt[tid * 8]     = w0;
      *(f32x4*)&Wt[tid * 8 + 4] = w1;
    }
    __syncthreads();
    float acc = 0.0f;
    for (int d = 0; d < 256; ++d) {
      float p = lsrow[d] * Wt[d * 8 + cl];   // separate mul
      acc = acc + p;                          // separate add, strict order
    }
    float xv = acc + bp[m * 256 + c0 + cl];
    XH[(size_t)m * 2097152 + (size_t)(c0 + cl) * 8192 + t0 + tl] = xv;
  }
}

// ---------- MFMA bf16 scan, TWO-PASS: exact min, then candidate collection ----------
// grid 512 = tt(64) * m(8); block = 4 waves, wave = 32 toks (2 MFMA row-tiles)
__global__ __launch_bounds__(256) void k_argmin(const float* __restrict__ XH,
                                                const unsigned short* __restrict__ CBb,
                                                const float* __restrict__ B32,
                                                int* __restrict__ cnts,
                                                unsigned short* __restrict__ lists) {
  int bx = blockIdx.x;
  int m = bx & 7, tt = bx >> 3;
  int t0 = tt * 128;
  __shared__ float Bs[4096];           // B32[m] staged (16KB)
  __shared__ unsigned int umin[128];
  __shared__ int lcnt[128];
  __shared__ unsigned short llist[128][16];
  int tid = threadIdx.x;
  {
    const f32x4* src = (const f32x4*)(B32 + m * 4096);
    f32x4* dst = (f32x4*)Bs;
#pragma unroll
    for (int i = 0; i < 4; ++i) dst[tid + 256 * i] = src[tid + 256 * i];
  }
  if (tid < 128) { umin[tid] = 0xFFFFFFFFu; lcnt[tid] = 0; }
  int w = tid >> 6, l = tid & 63;
  int row = l & 15, grp = l >> 4;      // A/B fragment row (=tok for A, =k for B); c-group
  const float FINF = __builtin_inff();

  // block-local token slots for this lane's accumulator rows
  int tloc[8];
#pragma unroll
  for (int r = 0; r < 4; ++r) {
    tloc[r]     = w * 32 + grp * 4 + r;        // a=0
    tloc[4 + r] = w * 32 + 16 + grp * 4 + r;   // a=1
  }

  // A-fragments: lane l holds X[tok = base + (l&15)][c = cs*32 + grp*8 + j], bf16
  bf16x8 afrag0[8], afrag1[8];
  {
    const float* xbase = XH + (size_t)m * 2097152;   // [c][t]
#pragma unroll
    for (int cs = 0; cs < 8; ++cs) {
      union { short s[8]; bf16x8 v; } u0, u1;
#pragma unroll
      for (int j = 0; j < 8; ++j) {
        int c = cs * 32 + grp * 8 + j;
        float x0 = xbase[(size_t)c * 8192 + t0 + w * 32 + row];
        float x1 = xbase[(size_t)c * 8192 + t0 + w * 32 + 16 + row];
        __hip_bfloat16 h0 = __float2bfloat16(x0);
        __hip_bfloat16 h1 = __float2bfloat16(x1);
        u0.s[j] = *reinterpret_cast<short*>(&h0);
        u1.s[j] = *reinterpret_cast<short*>(&h1);
      }
      afrag0[cs] = u0.v; afrag1[cs] = u1.v;
    }
  }
  __syncthreads();                     // Bs + umin/lcnt ready

  const unsigned short* cbbase = CBb + (size_t)m * 1048576 + (size_t)row * 256 + grp * 8;

  auto load_b = [&](int kt, bf16x8* bf) {
    const unsigned short* p = cbbase + (size_t)kt * 4096;
#pragma unroll
    for (int cs = 0; cs < 8; ++cs) bf[cs] = *(const bf16x8*)(p + cs * 32);
  };
  auto mfma_tile = [&](const bf16x8* bf, f32x4& a0, f32x4& a1) {
    a0 = f32x4{0.f,0.f,0.f,0.f}; a1 = f32x4{0.f,0.f,0.f,0.f};
#pragma unroll
    for (int cs = 0; cs < 8; ++cs) {
      a0 = __builtin_amdgcn_mfma_f32_16x16x32_bf16(afrag0[cs], bf[cs], a0, 0, 0, 0);
      a1 = __builtin_amdgcn_mfma_f32_16x16x32_bf16(afrag1[cs], bf[cs], a1, 0, 0, 0);
    }
  };

  bf16x8 bcur[8], bnxt[8];
  // ---- PASS A: exact min over all 4096 k (registers only) ----
  float rmin[8];
#pragma unroll
  for (int sl = 0; sl < 8; ++sl) rmin[sl] = FINF;
  load_b(0, bcur);
  for (int kt = 0; kt < 256; kt += 2) {
    load_b(kt + 1, bnxt);
    {
      f32x4 a0, a1; mfma_tile(bcur, a0, a1);
      float Bv = Bs[kt * 16 + row];
#pragma unroll
      for (int r = 0; r < 4; ++r) {
        rmin[r]     = fminf(rmin[r],     fmaf(-2.0f, a0[r], Bv));
        rmin[4 + r] = fminf(rmin[4 + r], fmaf(-2.0f, a1[r], Bv));
      }
    }
    if (kt + 2 < 256) load_b(kt + 2, bcur);
    {
      f32x4 a0, a1; mfma_tile(bnxt, a0, a1);
      float Bv = Bs[(kt + 1) * 16 + row];
#pragma unroll
      for (int r = 0; r < 4; ++r) {
        rmin[r]     = fminf(rmin[r],     fmaf(-2.0f, a0[r], Bv));
        rmin[4 + r] = fminf(rmin[4 + r], fmaf(-2.0f, a1[r], Bv));
      }
    }
  }
#pragma unroll
  for (int sl = 0; sl < 8; ++sl) atomicMin(&umin[tloc[sl]], fkey(rmin[sl]));
  __syncthreads();
  float thr[8];
#pragma unroll
  for (int sl = 0; sl < 8; ++sl) thr[sl] = funkey(umin[tloc[sl]]) + DELTA;

  // ---- PASS B: recompute, insert candidates vs FINAL threshold ----
  auto process = [&](int kt, const bf16x8* bf) {
    f32x4 a0, a1; mfma_tile(bf, a0, a1);
    float Bv = Bs[kt * 16 + row];
    int k = (kt << 4) + row;
#pragma unroll
    for (int r = 0; r < 4; ++r) {
      float s0 = fmaf(-2.0f, a0[r], Bv);
      float s1 = fmaf(-2.0f, a1[r], Bv);
      if (s0 <= thr[r]) {
        int pos = atomicAdd(&lcnt[tloc[r]], 1);
        if (pos < 16) llist[tloc[r]][pos] = (unsigned short)k;
      }
      if (s1 <= thr[4 + r]) {
        int pos = atomicAdd(&lcnt[tloc[4 + r]], 1);
        if (pos < 16) llist[tloc[4 + r]][pos] = (unsigned short)k;
      }
    }
  };
  load_b(0, bcur);
  for (int kt = 0; kt < 256; kt += 2) {
    load_b(kt + 1, bnxt);
    process(kt, bcur);
    if (kt + 2 < 256) load_b(kt + 2, bcur);
    process(kt + 1, bnxt);
  }

  __syncthreads();
  if (tid < 128) cnts[(size_t)(t0 + tid) * 8 + m] = lcnt[tid];
  {
    int e = tid;                       // 256 threads copy 2048 entries
#pragma unroll
    for (int rr = 0; rr < 8; ++rr, e += 256) {
      int tok = e >> 4, pos = e & 15;
      lists[((size_t)((t0 + tok) * 8 + m)) * 16 + pos] = llist[tok][pos];
    }
  }
}

// ---------- np-f32-exact final selection among candidates ----------
__global__ __launch_bounds__(256) void k_select(const float* __restrict__ XH,
                                                const float* __restrict__ cb,
                                                const float* __restrict__ B32,
                                                const int* __restrict__ cnts,
                                                const unsigned short* __restrict__ lists,
                                                int* __restrict__ idxp) {
#pragma clang fp contract(off)
  int bx = blockIdx.x;                 // grid 1024 = tt(128) * m(8)
  int m = bx & 7, tt = bx >> 3;
  int t0 = tt * 64;
  __shared__ float XT2[256 * 65];      // padded [c][t]
  __shared__ float Atok[64];
  __shared__ int ovlist[64];
  __shared__ int ovcnt;
  __shared__ float bvD[64];
  __shared__ int bvK[64];
  int tid = threadIdx.x;
  const float* xsrc = XH + (size_t)m * 2097152;
#pragma unroll
  for (int i = 0; i < 16; ++i) {
    int f = tid + 256 * i;
    int c = f >> 4, to = (f & 15) * 4;
    f32x4 v = *(const f32x4*)(xsrc + (size_t)c * 8192 + t0 + to);
    XT2[c*65+to+0]=v[0]; XT2[c*65+to+1]=v[1]; XT2[c*65+to+2]=v[2]; XT2[c*65+to+3]=v[3];
  }
  if (tid == 0) ovcnt = 0;
  __syncthreads();
  if (tid < 64) Atok[tid] = np_pw256sq(&XT2[tid], 65);   // np.sum(x*x) emulation
  __syncthreads();
  int q = tid >> 2, j = tid & 3;       // 64 quads (token t0+q) x 4 SSE lanes
  const float* cbm = cb + (size_t)m * 1048576;

  auto dist_np = [&](int k, int qq, float A) -> float {
#pragma clang fp contract(off)
    const float* row = cbm + (size_t)k * 256;
    float s = 0.0f;
    for (int i8 = 0; i8 < 256; i8 += 8) {
      float p0 = XT2[(i8 + j) * 65 + qq] * row[i8 + j];
      s = s + p0;
      float p1 = XT2[(i8 + 4 + j) * 65 + qq] * row[i8 + 4 + j];
      s = s + p1;
    }
    float o  = __shfl_xor(s, 1, 64);
    float ts = s + o;
    float o2 = __shfl_xor(ts, 2, 64);
    float red = ts + o2;               // (s0+s1)+(s2+s3)
    float T1 = A + B32[m * 4096 + k];  // fl(A + Bk)
    return T1 - 2.0f * red;            // fl(T1 - fl(2E))
  };

  int t8m = (t0 + q) * 8 + m;
  int n = cnts[t8m];
  float A = Atok[q];
  if (n <= 16) {
    float best = __builtin_inff();
    int bk = 0;
    for (int ci = 0; ci < n; ++ci) {
      int k = (int)lists[(size_t)t8m * 16 + ci] & 4095;
      float d2 = dist_np(k, q, A);
      if (d2 < best || (d2 == best && k < bk)) { best = d2; bk = k; }
    }
    if (j == 0) idxp[t8m] = bk;
  } else {
    if (j == 0) { int pos = atomicAdd(&ovcnt, 1); ovlist[pos] = q; }
  }
  __syncthreads();
  int ovn = ovcnt;
  for (int e = 0; e < ovn; ++e) {      // block-cooperative full scan per overflow token
    int qq = ovlist[e];
    float Aq = Atok[qq];
    float bd = __builtin_inff(); int bk2 = 0;
    for (int it = 0; it < 64; ++it) {
      int k = it * 64 + q;
      float d2 = dist_np(k, qq, Aq);
      if (d2 < bd) { bd = d2; bk2 = k; }
    }
    if (j == 0) { bvD[q] = bd; bvK[q] = bk2; }
    __syncthreads();
    if (tid == 0) {
      float bb = bvD[0]; int kk2 = bvK[0];
      for (int r = 1; r < 64; ++r) {
        if (bvD[r] < bb || (bvD[r] == bb && bvK[r] < kk2)) { bb = bvD[r]; kk2 = bvK[r]; }
      }
      idxp[(t0 + qq) * 8 + m] = kk2;
    }
    __syncthreads();
  }
}

// ---------- out = q@Wo + bo (f32), plus per-block loss partials ----------
__global__ __launch_bounds__(256) void k_out(const float* __restrict__ cb,
                                             const float* __restrict__ Wo,
                                             const float* __restrict__ bo,
                                             const float* __restrict__ XH,
                                             const int* __restrict__ idxp,
                                             float* __restrict__ outp,
                                             double* __restrict__ lossp) {
  int bx = blockIdx.x;                 // grid 2048 = tt(256) * m(8)
  int m = bx & 7, tt = bx >> 3;
  int t0 = tt * 32;
  __shared__ float qT[256 * 32];       // [c][t] 32KB
  __shared__ float Wl[64 * 256];       // [c][d] 64KB
  __shared__ double red[256];
  int tid = threadIdx.x;
  {
    int tok = tid & 31, g = tid >> 5;
    int ix = idxp[(size_t)(t0 + tok) * 8 + m] & 4095;
    const float* qrow = cb + ((size_t)m * 4096 + ix) * 256;
#pragma unroll
    for (int i = 0; i < 8; ++i) {
      int c = (g * 8 + i) * 4;
      f32x4 v = *(const f32x4*)(qrow + c);
      qT[(c+0)*32+tok]=v[0]; qT[(c+1)*32+tok]=v[1]; qT[(c+2)*32+tok]=v[2]; qT[(c+3)*32+tok]=v[3];
    }
  }
  int tg = tid & 7, dg = tid >> 3;     // 8 tok-groups(4 tok) x 32 d-groups(8 d)
  float acc[4][8] = {};
  const float* wbase = Wo + (size_t)m * 65536;
  for (int c4 = 0; c4 < 4; ++c4) {
    __syncthreads();
#pragma unroll
    for (int i = 0; i < 16; ++i) {
      int f = tid + 256 * i;
      int cr = f >> 6, doff = (f & 63) * 4;
      *(f32x4*)&Wl[f * 4] = *(const f32x4*)(wbase + (size_t)(c4 * 64 + cr) * 256 + doff);
    }
    __syncthreads();
#pragma unroll 4
    for (int c = 0; c < 64; ++c) {
      f32x4 q4 = *(const f32x4*)&qT[(c4 * 64 + c) * 32 + tg * 4];
      f32x4 w0 = *(const f32x4*)&Wl[c * 256 + dg * 8];
      f32x4 w1 = *(const f32x4*)&Wl[c * 256 + dg * 8 + 4];
#pragma unroll
      for (int i = 0; i < 4; ++i) {
        acc[i][0]+=q4[i]*w0[0]; acc[i][1]+=q4[i]*w0[1]; acc[i][2]+=q4[i]*w0[2]; acc[i][3]+=q4[i]*w0[3];
        acc[i][4]+=q4[i]*w1[0]; acc[i][5]+=q4[i]*w1[1]; acc[i][6]+=q4[i]*w1[2]; acc[i][7]+=q4[i]*w1[3];
      }
    }
  }
#pragma unroll
  for (int i = 0; i < 4; ++i) {
    int t = t0 + tg * 4 + i;
    f32x4 lo, hi;
#pragma unroll
    for (int jj = 0; jj < 4; ++jj) {
      lo[jj] = acc[i][jj]     + bo[m * 256 + dg * 8 + jj];
      hi[jj] = acc[i][jj + 4] + bo[m * 256 + dg * 8 + 4 + jj];
    }
    float* dst = outp + (size_t)t * 2048 + m * 256 + dg * 8;
    *(f32x4*)(dst)     = lo;
    *(f32x4*)(dst + 4) = hi;
  }
  float lp = 0.0f;
  {
    int ltok = tid & 31, cg2 = tid >> 5;
    const float* xg = XH + (size_t)m * 2097152 + t0 + ltok;
    for (int c = cg2 * 32; c < cg2 * 32 + 32; ++c) {
      float qv = qT[c * 32 + ltok];
      float xv = xg[(size_t)c * 8192];
      float d = qv - xv; lp += d * d;
    }
  }
  red[tid] = (double)lp;
  __syncthreads();
  for (int off = 128; off; off >>= 1) { if (tid < off) red[tid] += red[tid + off]; __syncthreads(); }
  if (tid == 0) lossp[bx] = red[0];
}

// ---------- finalize loss (f32 at outp[16777216]) ----------
__global__ void k_final(const double* __restrict__ lossp, float* __restrict__ outp) {
  __shared__ double red[256];
  int tid = threadIdx.x;
  double s = 0.0;
  for (int i = 0; i < 8; ++i) s += lossp[tid + 256 * i];
  red[tid] = s; __syncthreads();
  for (int off = 128; off; off >>= 1) { if (tid < off) red[tid] += red[tid + off]; __syncthreads(); }
  if (tid == 0) outp[16777216] = (float)(1.25 * red[0] / 16777216.0);
}

// ---------- idx -> f32 ----------
__global__ void k_idxout(const int* __restrict__ idxp, float* __restrict__ outp) {
  int i = blockIdx.x * 256 + threadIdx.x;
  outp[16777217 + i] = (float)idxp[i];
}

extern "C" void kernel_launch(void* const* d_in, const int* in_sizes, int n_in,
                              void* d_out, int out_size, void* d_ws, size_t ws_size,
                              hipStream_t stream) {
  (void)in_sizes; (void)n_in; (void)out_size; (void)ws_size;
  const float* slots = (const float*)d_in[0];
  const float* Wp    = (const float*)d_in[1];
  const float* bp    = (const float*)d_in[2];
  const float* cb    = (const float*)d_in[3];
  const float* Wo    = (const float*)d_in[4];
  const float* bo    = (const float*)d_in[5];
  float* outp = (float*)d_out;
  char* ws = (char*)d_ws;
  double*         lossp = (double*)(ws + WS_LOSSP);
  float*          B32   = (float*)(ws + WS_B32);
  int*            idxp  = (int*)(ws + WS_IDX);
  int*            cnts  = (int*)(ws + WS_CNT);
  unsigned short* lists = (unsigned short*)(ws + WS_LST);
  float*          XH    = (float*)(ws + WS_XH);
  unsigned short* CBb   = (unsigned short*)(ws + WS_CBT);

  k_cbnormB<<<128,  256, 0, stream>>>(cb, B32);
  k_cbb    <<<4096, 256, 0, stream>>>(cb, CBb);
  k_xhat   <<<2048, 256, 0, stream>>>(slots, Wp, bp, XH);
  k_argmin <<<512,  256, 0, stream>>>(XH, CBb, B32, cnts, lists);
  k_select <<<1024, 256, 0, stream>>>(XH, cb, B32, cnts, lists, idxp);
  k_out    <<<2048, 256, 0, stream>>>(cb, Wo, bo, XH, idxp, outp, lossp);
  k_final  <<<1,    256, 0, stream>>>(lossp, outp);
  k_idxout <<<256,  256, 0, stream>>>(idxp, outp);
}

// Round 8
// 1035.594 us; speedup vs baseline: 7.2616x; 1.5880x over previous
//
#include <hip/hip_runtime.h>
#include <hip/hip_bf16.h>

typedef float f32x4 __attribute__((ext_vector_type(4)));
typedef short bf16x8 __attribute__((ext_vector_type(8)));

// ---- workspace layout (bytes) ----
static constexpr size_t WS_LOSSP = 0;         // double[2048]               -> 16384
static constexpr size_t WS_B32   = 294912;    // float[32768] np-exact B    -> 425984
static constexpr size_t WS_IDX   = 425984;    // int[65536]                 -> 688128
static constexpr size_t WS_CNT   = 688128;    // int[65536] cand counts     -> 950272
static constexpr size_t WS_LST   = 950272;    // ushort[65536*16] cand list -> 3047424
static constexpr size_t WS_XH    = 3145728;   // float[8*256*8192] 64MB     -> 70254592
static constexpr size_t WS_CBT   = 70254592;  // ushort bf16[8][4096][256]  -> 87031808

#define DELTA 3.0e-4f

__device__ inline float b2f(unsigned short u) {
  unsigned int i = ((unsigned int)u) << 16; return __uint_as_float(i);
}
__device__ inline unsigned int fkey(float f) {
  unsigned int b = __float_as_uint(f); return (b & 0x80000000u) ? ~b : (b | 0x80000000u);
}
__device__ inline float funkey(unsigned int u) {
  unsigned int b = (u & 0x80000000u) ? (u ^ 0x80000000u) : ~u; return __uint_as_float(b);
}

// numpy pairwise_sum of 256 SQUARES, AVX512 width-16 emulation
__device__ inline float np_pw256sq(const float* p, int stride) {
#pragma clang fp contract(off)
  float h2[2];
#pragma unroll
  for (int hh = 0; hh < 2; ++hh) {
    const float* q = p + (size_t)(hh * 128) * stride;
    float V[16];
#pragma unroll
    for (int i = 0; i < 16; ++i) {
      float e[8];
#pragma unroll
      for (int j = 0; j < 8; ++j) { float x = q[(size_t)(j * 16 + i) * stride]; e[j] = x * x; }
      float t01 = e[0] + e[1], t23 = e[2] + e[3], t45 = e[4] + e[5], t67 = e[6] + e[7];
      float ta = t01 + t23, tb = t45 + t67;
      V[i] = ta + tb;
    }
    float u[8];
#pragma unroll
    for (int i = 0; i < 8; ++i) u[i] = V[i] + V[8 + i];
    float w[4];
#pragma unroll
    for (int i = 0; i < 4; ++i) w[i] = u[i] + u[4 + i];
    float wa = w[0] + w[2], wb = w[1] + w[3];
    h2[hh] = wa + wb;
  }
  return h2[0] + h2[1];
}

// ---------- np-exact codebook row norms ----------
__global__ __launch_bounds__(256) void k_cbnormB(const float* __restrict__ cb,
                                                 float* __restrict__ B32) {
  int row = blockIdx.x * 256 + threadIdx.x;      // grid 128 -> 32768 rows
  B32[row] = np_pw256sq(cb + (size_t)row * 256, 1);
}

// ---------- bf16 compress codebooks (layout preserved: [m][k][c]) ----------
__global__ __launch_bounds__(256) void k_cbb(const float* __restrict__ cb,
                                             unsigned short* __restrict__ cbb) {
  size_t i = ((size_t)blockIdx.x * 256 + threadIdx.x) * 8;   // grid 4096 -> 8.39M elems
  f32x4 v0 = *(const f32x4*)(cb + i);
  f32x4 v1 = *(const f32x4*)(cb + i + 4);
  union { unsigned short s[8]; uint4 u; } o;
#pragma unroll
  for (int j = 0; j < 4; ++j) {
    __hip_bfloat16 h0 = __float2bfloat16(v0[j]);
    __hip_bfloat16 h1 = __float2bfloat16(v1[j]);
    o.s[j]     = *reinterpret_cast<unsigned short*>(&h0);
    o.s[4 + j] = *reinterpret_cast<unsigned short*>(&h1);
  }
  *(uint4*)(cbb + i) = o.u;
}

// ---------- x-hat: np.einsum-exact (sequential d, no FMA), stored XH[m][c][t] ----------
__global__ __launch_bounds__(256) void k_xhat(const float* __restrict__ slots,
                                              const float* __restrict__ Wp,
                                              const float* __restrict__ bp,
                                              float* __restrict__ XH) {
#pragma clang fp contract(off)
  int bx = blockIdx.x;                 // grid 2048 = m(8) * tt(256)
  int m = bx & 7, tt = bx >> 3;
  int t0 = tt * 32;
  __shared__ float Ls[32 * 257];
  __shared__ float Wt[256 * 8];
  int tid = threadIdx.x;
  {
    int r = tid >> 3, q = tid & 7;     // 32 rows x 8 segments of 32 floats
    const float* src = slots + (size_t)(t0 + r) * 2048 + m * 256 + q * 32;
    float* dstrow = &Ls[r * 257 + q * 32];
#pragma unroll
    for (int e = 0; e < 8; ++e) {
      f32x4 v = *(const f32x4*)(src + e * 4);
      dstrow[e*4+0]=v[0]; dstrow[e*4+1]=v[1]; dstrow[e*4+2]=v[2]; dstrow[e*4+3]=v[3];
    }
  }
  int tl = tid & 31, cl = tid >> 5;    // 32 tokens x 8 channels
  const float* lsrow = &Ls[tl * 257];
  for (int cg = 0; cg < 32; ++cg) {
    int c0 = cg * 8;
    __syncthreads();                   // covers Ls staging (first iter) + Wt reuse hazard
    {
      const float* wsrc = Wp + (size_t)m * 65536 + (size_t)tid * 256 + c0;
      f32x4 w0 = *(const f32x4*)(wsrc);
      f32x4 w1 = *(const f32x4*)(wsrc + 4);
      *(f32x4*)&Wt[tid * 8]     = w0;
      *(f32x4*)&Wt[tid * 8 + 4] = w1;
    }
    __syncthreads();
    float acc = 0.0f;
    for (int d = 0; d < 256; ++d) {
      float p = lsrow[d] * Wt[d * 8 + cl];   // separate mul
      acc = acc + p;                          // separate add, strict order
    }
    float xv = acc + bp[m * 256 + c0 + cl];
    XH[(size_t)m * 2097152 + (size_t)(c0 + cl) * 8192 + t0 + tl] = xv;
  }
}

// ---------- MFMA bf16 scan, TWO-PASS, LDS-staged B (double-buffered) ----------
// grid 512 = tt(64) * m(8); block = 4 waves, wave = 32 toks (2 MFMA row-tiles)
__global__ __launch_bounds__(256) void k_argmin(const float* __restrict__ XH,
                                                const unsigned short* __restrict__ CBb,
                                                const float* __restrict__ B32,
                                                int* __restrict__ cnts,
                                                unsigned short* __restrict__ lists) {
  int bx = blockIdx.x;
  int m = bx & 7, tt = bx >> 3;
  int t0 = tt * 128;
  __shared__ unsigned short Bt[2][16 * 264];   // B tile, padded rows (528B) -> even bank spread
  __shared__ float Bs[4096];                   // B32[m] staged (16KB)
  __shared__ unsigned int umin[128];
  __shared__ int lcnt[128];
  __shared__ unsigned short llist[128][16];
  int tid = threadIdx.x;
  {
    const f32x4* src = (const f32x4*)(B32 + m * 4096);
    f32x4* dst = (f32x4*)Bs;
#pragma unroll
    for (int i = 0; i < 4; ++i) dst[tid + 256 * i] = src[tid + 256 * i];
  }
  if (tid < 128) { umin[tid] = 0xFFFFFFFFu; lcnt[tid] = 0; }
  int w = tid >> 6, l = tid & 63;
  int row = l & 15, grp = l >> 4;      // A/B fragment row (=tok for A, =k for B); c-group
  const float FINF = __builtin_inff();

  int tloc[8];
#pragma unroll
  for (int r = 0; r < 4; ++r) {
    tloc[r]     = w * 32 + grp * 4 + r;        // a=0
    tloc[4 + r] = w * 32 + 16 + grp * 4 + r;   // a=1
  }

  // A-fragments: lane l holds X[tok = base + (l&15)][c = cs*32 + grp*8 + j], bf16
  bf16x8 afrag0[8], afrag1[8];
  {
    const float* xbase = XH + (size_t)m * 2097152;   // [c][t]
#pragma unroll
    for (int cs = 0; cs < 8; ++cs) {
      union { short s[8]; bf16x8 v; } u0, u1;
#pragma unroll
      for (int j = 0; j < 8; ++j) {
        int c = cs * 32 + grp * 8 + j;
        float x0 = xbase[(size_t)c * 8192 + t0 + w * 32 + row];
        float x1 = xbase[(size_t)c * 8192 + t0 + w * 32 + 16 + row];
        __hip_bfloat16 h0 = __float2bfloat16(x0);
        __hip_bfloat16 h1 = __float2bfloat16(x1);
        u0.s[j] = *reinterpret_cast<short*>(&h0);
        u1.s[j] = *reinterpret_cast<short*>(&h1);
      }
      afrag0[cs] = u0.v; afrag1[cs] = u1.v;
    }
  }

  const uint4* cbsrc = (const uint4*)(CBb + (size_t)m * 1048576);
  uint4 pre0, pre1;
  auto sload = [&](int kt) {           // global -> regs (8KB tile, 512 uint4)
    const uint4* s = cbsrc + (size_t)kt * 512;
    pre0 = s[tid]; pre1 = s[tid + 256];
  };
  auto swrite = [&](int b) {           // regs -> LDS, padded rows
    int f0 = tid, f1 = tid + 256;      // 16B chunk index; row = f>>5, u = f&31
    *(uint4*)&Bt[b][(f0 >> 5) * 264 + (f0 & 31) * 8] = pre0;
    *(uint4*)&Bt[b][(f1 >> 5) * 264 + (f1 & 31) * 8] = pre1;
  };
  auto ld_frags = [&](int b, bf16x8* bf) {
#pragma unroll
    for (int cs = 0; cs < 8; ++cs)
      bf[cs] = *(const bf16x8*)&Bt[b][row * 264 + grp * 8 + cs * 32];
  };
  auto mfma_tile = [&](const bf16x8* bf, f32x4& a0, f32x4& a1) {
    a0 = f32x4{0.f,0.f,0.f,0.f}; a1 = f32x4{0.f,0.f,0.f,0.f};
#pragma unroll
    for (int cs = 0; cs < 8; ++cs) {
      a0 = __builtin_amdgcn_mfma_f32_16x16x32_bf16(afrag0[cs], bf[cs], a0, 0, 0, 0);
      a1 = __builtin_amdgcn_mfma_f32_16x16x32_bf16(afrag1[cs], bf[cs], a1, 0, 0, 0);
    }
  };

  // ---- PASS A: exact min over all 4096 k ----
  float rmin[8];
#pragma unroll
  for (int sl = 0; sl < 8; ++sl) rmin[sl] = FINF;
  sload(0); swrite(0); sload(1);
  __syncthreads();                     // Bt[0], Bs, umin/lcnt ready
  for (int kt = 0; kt < 256; ++kt) {
    int b = kt & 1;
    if (kt + 1 < 256) {                // write tile kt+1 (safe: b^1 last read 2 iters ago)
      swrite(b ^ 1);
      if (kt + 2 < 256) sload(kt + 2);
    }
    bf16x8 bf[8]; ld_frags(b, bf);
    f32x4 a0, a1; mfma_tile(bf, a0, a1);
    float Bv = Bs[kt * 16 + row];
#pragma unroll
    for (int r = 0; r < 4; ++r) {
      rmin[r]     = fminf(rmin[r],     fmaf(-2.0f, a0[r], Bv));
      rmin[4 + r] = fminf(rmin[4 + r], fmaf(-2.0f, a1[r], Bv));
    }
    __syncthreads();                   // reads of buf b done; written b^1 visible next iter
  }
#pragma unroll
  for (int sl = 0; sl < 8; ++sl) atomicMin(&umin[tloc[sl]], fkey(rmin[sl]));
  __syncthreads();
  float thr[8];
#pragma unroll
  for (int sl = 0; sl < 8; ++sl) thr[sl] = funkey(umin[tloc[sl]]) + DELTA;

  // ---- PASS B: recompute, insert candidates vs FINAL threshold ----
  sload(0); swrite(0); sload(1);
  __syncthreads();
  for (int kt = 0; kt < 256; ++kt) {
    int b = kt & 1;
    if (kt + 1 < 256) {
      swrite(b ^ 1);
      if (kt + 2 < 256) sload(kt + 2);
    }
    bf16x8 bf[8]; ld_frags(b, bf);
    f32x4 a0, a1; mfma_tile(bf, a0, a1);
    float Bv = Bs[kt * 16 + row];
    int k = (kt << 4) + row;
#pragma unroll
    for (int r = 0; r < 4; ++r) {
      float s0 = fmaf(-2.0f, a0[r], Bv);
      float s1 = fmaf(-2.0f, a1[r], Bv);
      if (s0 <= thr[r]) {
        int pos = atomicAdd(&lcnt[tloc[r]], 1);
        if (pos < 16) llist[tloc[r]][pos] = (unsigned short)k;
      }
      if (s1 <= thr[4 + r]) {
        int pos = atomicAdd(&lcnt[tloc[4 + r]], 1);
        if (pos < 16) llist[tloc[4 + r]][pos] = (unsigned short)k;
      }
    }
    __syncthreads();
  }

  if (tid < 128) cnts[(size_t)(t0 + tid) * 8 + m] = lcnt[tid];
  {
    int e = tid;                       // 256 threads copy 2048 entries
#pragma unroll
    for (int rr = 0; rr < 8; ++rr, e += 256) {
      int tok = e >> 4, pos = e & 15;
      lists[((size_t)((t0 + tok) * 8 + m)) * 16 + pos] = llist[tok][pos];
    }
  }
}

// ---------- np-f32-exact final selection among candidates ----------
__global__ __launch_bounds__(256) void k_select(const float* __restrict__ XH,
                                                const float* __restrict__ cb,
                                                const float* __restrict__ B32,
                                                const int* __restrict__ cnts,
                                                const unsigned short* __restrict__ lists,
                                                int* __restrict__ idxp) {
#pragma clang fp contract(off)
  int bx = blockIdx.x;                 // grid 1024 = tt(128) * m(8)
  int m = bx & 7, tt = bx >> 3;
  int t0 = tt * 64;
  __shared__ float XT2[256 * 65];      // padded [c][t]
  __shared__ float Atok[64];
  __shared__ int ovlist[64];
  __shared__ int ovcnt;
  __shared__ float bvD[64];
  __shared__ int bvK[64];
  int tid = threadIdx.x;
  const float* xsrc = XH + (size_t)m * 2097152;
#pragma unroll
  for (int i = 0; i < 16; ++i) {
    int f = tid + 256 * i;
    int c = f >> 4, to = (f & 15) * 4;
    f32x4 v = *(const f32x4*)(xsrc + (size_t)c * 8192 + t0 + to);
    XT2[c*65+to+0]=v[0]; XT2[c*65+to+1]=v[1]; XT2[c*65+to+2]=v[2]; XT2[c*65+to+3]=v[3];
  }
  if (tid == 0) ovcnt = 0;
  __syncthreads();
  if (tid < 64) Atok[tid] = np_pw256sq(&XT2[tid], 65);   // np.sum(x*x) emulation
  __syncthreads();
  int q = tid >> 2, j = tid & 3;       // 64 quads (token t0+q) x 4 SSE lanes
  const float* cbm = cb + (size_t)m * 1048576;

  auto dist_np = [&](int k, int qq, float A) -> float {
#pragma clang fp contract(off)
    const float* row = cbm + (size_t)k * 256;
    float s = 0.0f;
    for (int i8 = 0; i8 < 256; i8 += 8) {
      float p0 = XT2[(i8 + j) * 65 + qq] * row[i8 + j];
      s = s + p0;
      float p1 = XT2[(i8 + 4 + j) * 65 + qq] * row[i8 + 4 + j];
      s = s + p1;
    }
    float o  = __shfl_xor(s, 1, 64);
    float ts = s + o;
    float o2 = __shfl_xor(ts, 2, 64);
    float red = ts + o2;               // (s0+s1)+(s2+s3)
    float T1 = A + B32[m * 4096 + k];  // fl(A + Bk)
    return T1 - 2.0f * red;            // fl(T1 - fl(2E))
  };

  int t8m = (t0 + q) * 8 + m;
  int n = cnts[t8m];
  float A = Atok[q];
  if (n <= 16) {
    float best = __builtin_inff();
    int bk = 0;
    for (int ci = 0; ci < n; ++ci) {
      int k = (int)lists[(size_t)t8m * 16 + ci] & 4095;
      float d2 = dist_np(k, q, A);
      if (d2 < best || (d2 == best && k < bk)) { best = d2; bk = k; }
    }
    if (j == 0) idxp[t8m] = bk;
  } else {
    if (j == 0) { int pos = atomicAdd(&ovcnt, 1); ovlist[pos] = q; }
  }
  __syncthreads();
  int ovn = ovcnt;
  for (int e = 0; e < ovn; ++e) {      // block-cooperative full scan per overflow token
    int qq = ovlist[e];
    float Aq = Atok[qq];
    float bd = __builtin_inff(); int bk2 = 0;
    for (int it = 0; it < 64; ++it) {
      int k = it * 64 + q;
      float d2 = dist_np(k, qq, Aq);
      if (d2 < bd) { bd = d2; bk2 = k; }
    }
    if (j == 0) { bvD[q] = bd; bvK[q] = bk2; }
    __syncthreads();
    if (tid == 0) {
      float bb = bvD[0]; int kk2 = bvK[0];
      for (int r = 1; r < 64; ++r) {
        if (bvD[r] < bb || (bvD[r] == bb && bvK[r] < kk2)) { bb = bvD[r]; kk2 = bvK[r]; }
      }
      idxp[(t0 + qq) * 8 + m] = kk2;
    }
    __syncthreads();
  }
}

// ---------- out = q@Wo + bo (f32), plus per-block loss partials ----------
__global__ __launch_bounds__(256) void k_out(const float* __restrict__ cb,
                                             const float* __restrict__ Wo,
                                             const float* __restrict__ bo,
                                             const float* __restrict__ XH,
                                             const int* __restrict__ idxp,
                                             float* __restrict__ outp,
                                             double* __restrict__ lossp) {
  int bx = blockIdx.x;                 // grid 2048 = tt(256) * m(8)
  int m = bx & 7, tt = bx >> 3;
  int t0 = tt * 32;
  __shared__ float qT[256 * 32];       // [c][t] 32KB
  __shared__ float Wl[64 * 256];       // [c][d] 64KB
  __shared__ double red[256];
  int tid = threadIdx.x;
  {
    int tok = tid & 31, g = tid >> 5;
    int ix = idxp[(size_t)(t0 + tok) * 8 + m] & 4095;
    const float* qrow = cb + ((size_t)m * 4096 + ix) * 256;
#pragma unroll
    for (int i = 0; i < 8; ++i) {
      int c = (g * 8 + i) * 4;
      f32x4 v = *(const f32x4*)(qrow + c);
      qT[(c+0)*32+tok]=v[0]; qT[(c+1)*32+tok]=v[1]; qT[(c+2)*32+tok]=v[2]; qT[(c+3)*32+tok]=v[3];
    }
  }
  int tg = tid & 7, dg = tid >> 3;     // 8 tok-groups(4 tok) x 32 d-groups(8 d)
  float acc[4][8] = {};
  const float* wbase = Wo + (size_t)m * 65536;
  for (int c4 = 0; c4 < 4; ++c4) {
    __syncthreads();
#pragma unroll
    for (int i = 0; i < 16; ++i) {
      int f = tid + 256 * i;
      int cr = f >> 6, doff = (f & 63) * 4;
      *(f32x4*)&Wl[f * 4] = *(const f32x4*)(wbase + (size_t)(c4 * 64 + cr) * 256 + doff);
    }
    __syncthreads();
#pragma unroll 4
    for (int c = 0; c < 64; ++c) {
      f32x4 q4 = *(const f32x4*)&qT[(c4 * 64 + c) * 32 + tg * 4];
      f32x4 w0 = *(const f32x4*)&Wl[c * 256 + dg * 8];
      f32x4 w1 = *(const f32x4*)&Wl[c * 256 + dg * 8 + 4];
#pragma unroll
      for (int i = 0; i < 4; ++i) {
        acc[i][0]+=q4[i]*w0[0]; acc[i][1]+=q4[i]*w0[1]; acc[i][2]+=q4[i]*w0[2]; acc[i][3]+=q4[i]*w0[3];
        acc[i][4]+=q4[i]*w1[0]; acc[i][5]+=q4[i]*w1[1]; acc[i][6]+=q4[i]*w1[2]; acc[i][7]+=q4[i]*w1[3];
      }
    }
  }
#pragma unroll
  for (int i = 0; i < 4; ++i) {
    int t = t0 + tg * 4 + i;
    f32x4 lo, hi;
#pragma unroll
    for (int jj = 0; jj < 4; ++jj) {
      lo[jj] = acc[i][jj]     + bo[m * 256 + dg * 8 + jj];
      hi[jj] = acc[i][jj + 4] + bo[m * 256 + dg * 8 + 4 + jj];
    }
    float* dst = outp + (size_t)t * 2048 + m * 256 + dg * 8;
    *(f32x4*)(dst)     = lo;
    *(f32x4*)(dst + 4) = hi;
  }
  float lp = 0.0f;
  {
    int ltok = tid & 31, cg2 = tid >> 5;
    const float* xg = XH + (size_t)m * 2097152 + t0 + ltok;
    for (int c = cg2 * 32; c < cg2 * 32 + 32; ++c) {
      float qv = qT[c * 32 + ltok];
      float xv = xg[(size_t)c * 8192];
      float d = qv - xv; lp += d * d;
    }
  }
  red[tid] = (double)lp;
  __syncthreads();
  for (int off = 128; off; off >>= 1) { if (tid < off) red[tid] += red[tid + off]; __syncthreads(); }
  if (tid == 0) lossp[bx] = red[0];
}

// ---------- finalize loss (f32 at outp[16777216]) ----------
__global__ void k_final(const double* __restrict__ lossp, float* __restrict__ outp) {
  __shared__ double red[256];
  int tid = threadIdx.x;
  double s = 0.0;
  for (int i = 0; i < 8; ++i) s += lossp[tid + 256 * i];
  red[tid] = s; __syncthreads();
  for (int off = 128; off; off >>= 1) { if (tid < off) red[tid] += red[tid + off]; __syncthreads(); }
  if (tid == 0) outp[16777216] = (float)(1.25 * red[0] / 16777216.0);
}

// ---------- idx -> f32 ----------
__global__ void k_idxout(const int* __restrict__ idxp, float* __restrict__ outp) {
  int i = blockIdx.x * 256 + threadIdx.x;
  outp[16777217 + i] = (float)idxp[i];
}

extern "C" void kernel_launch(void* const* d_in, const int* in_sizes, int n_in,
                              void* d_out, int out_size, void* d_ws, size_t ws_size,
                              hipStream_t stream) {
  (void)in_sizes; (void)n_in; (void)out_size; (void)ws_size;
  const float* slots = (const float*)d_in[0];
  const float* Wp    = (const float*)d_in[1];
  const float* bp    = (const float*)d_in[2];
  const float* cb    = (const float*)d_in[3];
  const float* Wo    = (const float*)d_in[4];
  const float* bo    = (const float*)d_in[5];
  float* outp = (float*)d_out;
  char* ws = (char*)d_ws;
  double*         lossp = (double*)(ws + WS_LOSSP);
  float*          B32   = (float*)(ws + WS_B32);
  int*            idxp  = (int*)(ws + WS_IDX);
  int*            cnts  = (int*)(ws + WS_CNT);
  unsigned short* lists = (unsigned short*)(ws + WS_LST);
  float*          XH    = (float*)(ws + WS_XH);
  unsigned short* CBb   = (unsigned short*)(ws + WS_CBT);

  k_cbnormB<<<128,  256, 0, stream>>>(cb, B32);
  k_cbb    <<<4096, 256, 0, stream>>>(cb, CBb);
  k_xhat   <<<2048, 256, 0, stream>>>(slots, Wp, bp, XH);
  k_argmin <<<512,  256, 0, stream>>>(XH, CBb, B32, cnts, lists);
  k_select <<<1024, 256, 0, stream>>>(XH, cb, B32, cnts, lists, idxp);
  k_out    <<<2048, 256, 0, stream>>>(cb, Wo, bo, XH, idxp, outp, lossp);
  k_final  <<<1,    256, 0, stream>>>(lossp, outp);
  k_idxout <<<256,  256, 0, stream>>>(idxp, outp);
}

// Round 9
// 781.139 us; speedup vs baseline: 9.6270x; 1.3257x over previous
//
#include <hip/hip_runtime.h>
#include <hip/hip_bf16.h>

typedef float f32x4 __attribute__((ext_vector_type(4)));
typedef short bf16x8 __attribute__((ext_vector_type(8)));

// ---- workspace layout (bytes) ----
static constexpr size_t WS_LOSSP = 0;         // double[2048]               -> 16384
static constexpr size_t WS_B32   = 294912;    // float[32768] np-exact B    -> 425984
static constexpr size_t WS_IDX   = 425984;    // int[65536]                 -> 688128
static constexpr size_t WS_CNT   = 688128;    // int[65536] cand counts     -> 950272
static constexpr size_t WS_LST   = 950272;    // ushort[65536*16] cand list -> 3047424
static constexpr size_t WS_XH    = 3145728;   // float[8*256*8192] 64MB     -> 70254592
static constexpr size_t WS_CBT   = 70254592;  // ushort bf16[8][4096][256]  -> 87031808

#define DELTA 3.0e-4f

__device__ inline float b2f(unsigned short u) {
  unsigned int i = ((unsigned int)u) << 16; return __uint_as_float(i);
}
__device__ inline unsigned int fkey(float f) {
  unsigned int b = __float_as_uint(f); return (b & 0x80000000u) ? ~b : (b | 0x80000000u);
}
__device__ inline float funkey(unsigned int u) {
  unsigned int b = (u & 0x80000000u) ? (u ^ 0x80000000u) : ~u; return __uint_as_float(b);
}

// numpy pairwise_sum of 256 SQUARES, AVX512 width-16 emulation
__device__ inline float np_pw256sq(const float* p, int stride) {
#pragma clang fp contract(off)
  float h2[2];
#pragma unroll
  for (int hh = 0; hh < 2; ++hh) {
    const float* q = p + (size_t)(hh * 128) * stride;
    float V[16];
#pragma unroll
    for (int i = 0; i < 16; ++i) {
      float e[8];
#pragma unroll
      for (int j = 0; j < 8; ++j) { float x = q[(size_t)(j * 16 + i) * stride]; e[j] = x * x; }
      float t01 = e[0] + e[1], t23 = e[2] + e[3], t45 = e[4] + e[5], t67 = e[6] + e[7];
      float ta = t01 + t23, tb = t45 + t67;
      V[i] = ta + tb;
    }
    float u[8];
#pragma unroll
    for (int i = 0; i < 8; ++i) u[i] = V[i] + V[8 + i];
    float w[4];
#pragma unroll
    for (int i = 0; i < 4; ++i) w[i] = u[i] + u[4 + i];
    float wa = w[0] + w[2], wb = w[1] + w[3];
    h2[hh] = wa + wb;
  }
  return h2[0] + h2[1];
}

// ---------- np-exact codebook row norms ----------
__global__ __launch_bounds__(256) void k_cbnormB(const float* __restrict__ cb,
                                                 float* __restrict__ B32) {
  int row = blockIdx.x * 256 + threadIdx.x;      // grid 128 -> 32768 rows
  B32[row] = np_pw256sq(cb + (size_t)row * 256, 1);
}

// ---------- bf16 compress codebooks (layout preserved: [m][k][c]) ----------
__global__ __launch_bounds__(256) void k_cbb(const float* __restrict__ cb,
                                             unsigned short* __restrict__ cbb) {
  size_t i = ((size_t)blockIdx.x * 256 + threadIdx.x) * 8;   // grid 4096 -> 8.39M elems
  f32x4 v0 = *(const f32x4*)(cb + i);
  f32x4 v1 = *(const f32x4*)(cb + i + 4);
  union { unsigned short s[8]; uint4 u; } o;
#pragma unroll
  for (int j = 0; j < 4; ++j) {
    __hip_bfloat16 h0 = __float2bfloat16(v0[j]);
    __hip_bfloat16 h1 = __float2bfloat16(v1[j]);
    o.s[j]     = *reinterpret_cast<unsigned short*>(&h0);
    o.s[4 + j] = *reinterpret_cast<unsigned short*>(&h1);
  }
  *(uint4*)(cbb + i) = o.u;
}

// ---------- x-hat: np.einsum-exact (sequential d, no FMA), 4 channels/thread ----------
// grid 2048 = m(8) * tt(256); 8 batches of 32 channels; per-output order unchanged
__global__ __launch_bounds__(256) void k_xhat(const float* __restrict__ slots,
                                              const float* __restrict__ Wp,
                                              const float* __restrict__ bp,
                                              float* __restrict__ XH) {
#pragma clang fp contract(off)
  int bx = blockIdx.x;
  int m = bx & 7, tt = bx >> 3;
  int t0 = tt * 32;
  __shared__ float Ls[32 * 257];       // [tok][d] stride 257 -> conflict-free scalar reads
  __shared__ float Wt[256 * 36];       // [d][32c + pad] rows 144B (16B-aligned) -> b128 reads
  int tid = threadIdx.x;
  {
    int r = tid >> 3, q = tid & 7;     // 32 rows x 8 segments of 32 floats
    const float* src = slots + (size_t)(t0 + r) * 2048 + m * 256 + q * 32;
    float* dstrow = &Ls[r * 257 + q * 32];
#pragma unroll
    for (int e = 0; e < 8; ++e) {
      f32x4 v = *(const f32x4*)(src + e * 4);
      dstrow[e*4+0]=v[0]; dstrow[e*4+1]=v[1]; dstrow[e*4+2]=v[2]; dstrow[e*4+3]=v[3];
    }
  }
  int tl = tid & 31, grp = tid >> 5;   // 32 tokens x 8 channel-groups (4 ch each per batch)
  const float* lsrow = &Ls[tl * 257];
  float* xgbase = XH + (size_t)m * 2097152 + t0 + tl;
  for (int batch = 0; batch < 8; ++batch) {
    int c0 = batch * 32;
    __syncthreads();                   // prev-batch Wt reads done (covers Ls staging, iter 0)
    {
      const float* wsrc = Wp + (size_t)m * 65536 + (size_t)tid * 256 + c0;
      float* wdst = &Wt[tid * 36];
#pragma unroll
      for (int e = 0; e < 8; ++e) *(f32x4*)(wdst + e * 4) = *(const f32x4*)(wsrc + e * 4);
    }
    __syncthreads();
    float a0 = 0.0f, a1 = 0.0f, a2 = 0.0f, a3 = 0.0f;   // 4 independent strict chains
#pragma unroll 4
    for (int d = 0; d < 256; ++d) {
      float x = lsrow[d];
      f32x4 w = *(const f32x4*)&Wt[d * 36 + grp * 4];
      float p0 = x * w[0]; a0 = a0 + p0;   // separate mul, separate add, d-order per output
      float p1 = x * w[1]; a1 = a1 + p1;
      float p2 = x * w[2]; a2 = a2 + p2;
      float p3 = x * w[3]; a3 = a3 + p3;
    }
    int cbase = c0 + grp * 4;
    const float* bpb = bp + m * 256 + cbase;
    xgbase[(size_t)(cbase + 0) * 8192] = a0 + bpb[0];
    xgbase[(size_t)(cbase + 1) * 8192] = a1 + bpb[1];
    xgbase[(size_t)(cbase + 2) * 8192] = a2 + bpb[2];
    xgbase[(size_t)(cbase + 3) * 8192] = a3 + bpb[3];
  }
}

// ---------- MFMA bf16 scan, TWO-PASS, LDS-staged B (double-buffered) ----------
// grid 512 = tt(64) * m(8); block = 4 waves, wave = 32 toks (2 MFMA row-tiles)
__global__ __launch_bounds__(256) void k_argmin(const float* __restrict__ XH,
                                                const unsigned short* __restrict__ CBb,
                                                const float* __restrict__ B32,
                                                int* __restrict__ cnts,
                                                unsigned short* __restrict__ lists) {
  int bx = blockIdx.x;
  int m = bx & 7, tt = bx >> 3;
  int t0 = tt * 128;
  __shared__ unsigned short Bt[2][16 * 264];   // B tile, padded rows (528B) -> even bank spread
  __shared__ float Bs[4096];                   // B32[m] staged (16KB)
  __shared__ unsigned int umin[128];
  __shared__ int lcnt[128];
  __shared__ unsigned short llist[128][16];
  int tid = threadIdx.x;
  {
    const f32x4* src = (const f32x4*)(B32 + m * 4096);
    f32x4* dst = (f32x4*)Bs;
#pragma unroll
    for (int i = 0; i < 4; ++i) dst[tid + 256 * i] = src[tid + 256 * i];
  }
  if (tid < 128) { umin[tid] = 0xFFFFFFFFu; lcnt[tid] = 0; }
  int w = tid >> 6, l = tid & 63;
  int row = l & 15, grp = l >> 4;      // A/B fragment row (=tok for A, =k for B); c-group
  const float FINF = __builtin_inff();

  int tloc[8];
#pragma unroll
  for (int r = 0; r < 4; ++r) {
    tloc[r]     = w * 32 + grp * 4 + r;        // a=0
    tloc[4 + r] = w * 32 + 16 + grp * 4 + r;   // a=1
  }

  // A-fragments: lane l holds X[tok = base + (l&15)][c = cs*32 + grp*8 + j], bf16
  bf16x8 afrag0[8], afrag1[8];
  {
    const float* xbase = XH + (size_t)m * 2097152;   // [c][t]
#pragma unroll
    for (int cs = 0; cs < 8; ++cs) {
      union { short s[8]; bf16x8 v; } u0, u1;
#pragma unroll
      for (int j = 0; j < 8; ++j) {
        int c = cs * 32 + grp * 8 + j;
        float x0 = xbase[(size_t)c * 8192 + t0 + w * 32 + row];
        float x1 = xbase[(size_t)c * 8192 + t0 + w * 32 + 16 + row];
        __hip_bfloat16 h0 = __float2bfloat16(x0);
        __hip_bfloat16 h1 = __float2bfloat16(x1);
        u0.s[j] = *reinterpret_cast<short*>(&h0);
        u1.s[j] = *reinterpret_cast<short*>(&h1);
      }
      afrag0[cs] = u0.v; afrag1[cs] = u1.v;
    }
  }

  const uint4* cbsrc = (const uint4*)(CBb + (size_t)m * 1048576);
  uint4 pre0, pre1;
  auto sload = [&](int kt) {           // global -> regs (8KB tile, 512 uint4)
    const uint4* s = cbsrc + (size_t)kt * 512;
    pre0 = s[tid]; pre1 = s[tid + 256];
  };
  auto swrite = [&](int b) {           // regs -> LDS, padded rows
    int f0 = tid, f1 = tid + 256;      // 16B chunk index; row = f>>5, u = f&31
    *(uint4*)&Bt[b][(f0 >> 5) * 264 + (f0 & 31) * 8] = pre0;
    *(uint4*)&Bt[b][(f1 >> 5) * 264 + (f1 & 31) * 8] = pre1;
  };
  auto ld_frags = [&](int b, bf16x8* bf) {
#pragma unroll
    for (int cs = 0; cs < 8; ++cs)
      bf[cs] = *(const bf16x8*)&Bt[b][row * 264 + grp * 8 + cs * 32];
  };
  auto mfma_tile = [&](const bf16x8* bf, f32x4& a0, f32x4& a1) {
    a0 = f32x4{0.f,0.f,0.f,0.f}; a1 = f32x4{0.f,0.f,0.f,0.f};
#pragma unroll
    for (int cs = 0; cs < 8; ++cs) {
      a0 = __builtin_amdgcn_mfma_f32_16x16x32_bf16(afrag0[cs], bf[cs], a0, 0, 0, 0);
      a1 = __builtin_amdgcn_mfma_f32_16x16x32_bf16(afrag1[cs], bf[cs], a1, 0, 0, 0);
    }
  };

  // ---- PASS A: exact min over all 4096 k ----
  float rmin[8];
#pragma unroll
  for (int sl = 0; sl < 8; ++sl) rmin[sl] = FINF;
  sload(0); swrite(0); sload(1);
  __syncthreads();                     // Bt[0], Bs, umin/lcnt ready
  for (int kt = 0; kt < 256; ++kt) {
    int b = kt & 1;
    if (kt + 1 < 256) {                // write tile kt+1 (safe: b^1 last read 2 iters ago)
      swrite(b ^ 1);
      if (kt + 2 < 256) sload(kt + 2);
    }
    bf16x8 bf[8]; ld_frags(b, bf);
    f32x4 a0, a1; mfma_tile(bf, a0, a1);
    float Bv = Bs[kt * 16 + row];
#pragma unroll
    for (int r = 0; r < 4; ++r) {
      rmin[r]     = fminf(rmin[r],     fmaf(-2.0f, a0[r], Bv));
      rmin[4 + r] = fminf(rmin[4 + r], fmaf(-2.0f, a1[r], Bv));
    }
    __syncthreads();                   // reads of buf b done; written b^1 visible next iter
  }
#pragma unroll
  for (int sl = 0; sl < 8; ++sl) atomicMin(&umin[tloc[sl]], fkey(rmin[sl]));
  __syncthreads();
  float thr[8];
#pragma unroll
  for (int sl = 0; sl < 8; ++sl) thr[sl] = funkey(umin[tloc[sl]]) + DELTA;

  // ---- PASS B: recompute, insert candidates vs FINAL threshold ----
  sload(0); swrite(0); sload(1);
  __syncthreads();
  for (int kt = 0; kt < 256; ++kt) {
    int b = kt & 1;
    if (kt + 1 < 256) {
      swrite(b ^ 1);
      if (kt + 2 < 256) sload(kt + 2);
    }
    bf16x8 bf[8]; ld_frags(b, bf);
    f32x4 a0, a1; mfma_tile(bf, a0, a1);
    float Bv = Bs[kt * 16 + row];
    int k = (kt << 4) + row;
#pragma unroll
    for (int r = 0; r < 4; ++r) {
      float s0 = fmaf(-2.0f, a0[r], Bv);
      float s1 = fmaf(-2.0f, a1[r], Bv);
      if (s0 <= thr[r]) {
        int pos = atomicAdd(&lcnt[tloc[r]], 1);
        if (pos < 16) llist[tloc[r]][pos] = (unsigned short)k;
      }
      if (s1 <= thr[4 + r]) {
        int pos = atomicAdd(&lcnt[tloc[4 + r]], 1);
        if (pos < 16) llist[tloc[4 + r]][pos] = (unsigned short)k;
      }
    }
    __syncthreads();
  }

  if (tid < 128) cnts[(size_t)(t0 + tid) * 8 + m] = lcnt[tid];
  {
    int e = tid;                       // 256 threads copy 2048 entries
#pragma unroll
    for (int rr = 0; rr < 8; ++rr, e += 256) {
      int tok = e >> 4, pos = e & 15;
      lists[((size_t)((t0 + tok) * 8 + m)) * 16 + pos] = llist[tok][pos];
    }
  }
}

// ---------- np-f32-exact final selection among candidates ----------
__global__ __launch_bounds__(256) void k_select(const float* __restrict__ XH,
                                                const float* __restrict__ cb,
                                                const float* __restrict__ B32,
                                                const int* __restrict__ cnts,
                                                const unsigned short* __restrict__ lists,
                                                int* __restrict__ idxp) {
#pragma clang fp contract(off)
  int bx = blockIdx.x;                 // grid 1024 = tt(128) * m(8)
  int m = bx & 7, tt = bx >> 3;
  int t0 = tt * 64;
  __shared__ float XT2[256 * 65];      // padded [c][t]
  __shared__ float Atok[64];
  __shared__ int ovlist[64];
  __shared__ int ovcnt;
  __shared__ float bvD[64];
  __shared__ int bvK[64];
  int tid = threadIdx.x;
  const float* xsrc = XH + (size_t)m * 2097152;
#pragma unroll
  for (int i = 0; i < 16; ++i) {
    int f = tid + 256 * i;
    int c = f >> 4, to = (f & 15) * 4;
    f32x4 v = *(const f32x4*)(xsrc + (size_t)c * 8192 + t0 + to);
    XT2[c*65+to+0]=v[0]; XT2[c*65+to+1]=v[1]; XT2[c*65+to+2]=v[2]; XT2[c*65+to+3]=v[3];
  }
  if (tid == 0) ovcnt = 0;
  __syncthreads();
  if (tid < 64) Atok[tid] = np_pw256sq(&XT2[tid], 65);   // np.sum(x*x) emulation
  __syncthreads();
  int q = tid >> 2, j = tid & 3;       // 64 quads (token t0+q) x 4 SSE lanes
  const float* cbm = cb + (size_t)m * 1048576;

  auto dist_np = [&](int k, int qq, float A) -> float {
#pragma clang fp contract(off)
    const float* row = cbm + (size_t)k * 256;
    float s = 0.0f;
    for (int i8 = 0; i8 < 256; i8 += 8) {
      float p0 = XT2[(i8 + j) * 65 + qq] * row[i8 + j];
      s = s + p0;
      float p1 = XT2[(i8 + 4 + j) * 65 + qq] * row[i8 + 4 + j];
      s = s + p1;
    }
    float o  = __shfl_xor(s, 1, 64);
    float ts = s + o;
    float o2 = __shfl_xor(ts, 2, 64);
    float red = ts + o2;               // (s0+s1)+(s2+s3)
    float T1 = A + B32[m * 4096 + k];  // fl(A + Bk)
    return T1 - 2.0f * red;            // fl(T1 - fl(2E))
  };

  int t8m = (t0 + q) * 8 + m;
  int n = cnts[t8m];
  float A = Atok[q];
  if (n <= 16) {
    float best = __builtin_inff();
    int bk = 0;
    for (int ci = 0; ci < n; ++ci) {
      int k = (int)lists[(size_t)t8m * 16 + ci] & 4095;
      float d2 = dist_np(k, q, A);
      if (d2 < best || (d2 == best && k < bk)) { best = d2; bk = k; }
    }
    if (j == 0) idxp[t8m] = bk;
  } else {
    if (j == 0) { int pos = atomicAdd(&ovcnt, 1); ovlist[pos] = q; }
  }
  __syncthreads();
  int ovn = ovcnt;
  for (int e = 0; e < ovn; ++e) {      // block-cooperative full scan per overflow token
    int qq = ovlist[e];
    float Aq = Atok[qq];
    float bd = __builtin_inff(); int bk2 = 0;
    for (int it = 0; it < 64; ++it) {
      int k = it * 64 + q;
      float d2 = dist_np(k, qq, Aq);
      if (d2 < bd) { bd = d2; bk2 = k; }
    }
    if (j == 0) { bvD[q] = bd; bvK[q] = bk2; }
    __syncthreads();
    if (tid == 0) {
      float bb = bvD[0]; int kk2 = bvK[0];
      for (int r = 1; r < 64; ++r) {
        if (bvD[r] < bb || (bvD[r] == bb && bvK[r] < kk2)) { bb = bvD[r]; kk2 = bvK[r]; }
      }
      idxp[(t0 + qq) * 8 + m] = kk2;
    }
    __syncthreads();
  }
}

// ---------- out = q@Wo + bo (f32), plus per-block loss partials ----------
__global__ __launch_bounds__(256) void k_out(const float* __restrict__ cb,
                                             const float* __restrict__ Wo,
                                             const float* __restrict__ bo,
                                             const float* __restrict__ XH,
                                             const int* __restrict__ idxp,
                                             float* __restrict__ outp,
                                             double* __restrict__ lossp) {
  int bx = blockIdx.x;                 // grid 2048 = tt(256) * m(8)
  int m = bx & 7, tt = bx >> 3;
  int t0 = tt * 32;
  __shared__ float qT[256 * 32];       // [c][t] 32KB
  __shared__ float Wl[64 * 256];       // [c][d] 64KB
  __shared__ double red[256];
  int tid = threadIdx.x;
  {
    int tok = tid & 31, g = tid >> 5;
    int ix = idxp[(size_t)(t0 + tok) * 8 + m] & 4095;
    const float* qrow = cb + ((size_t)m * 4096 + ix) * 256;
#pragma unroll
    for (int i = 0; i < 8; ++i) {
      int c = (g * 8 + i) * 4;
      f32x4 v = *(const f32x4*)(qrow + c);
      qT[(c+0)*32+tok]=v[0]; qT[(c+1)*32+tok]=v[1]; qT[(c+2)*32+tok]=v[2]; qT[(c+3)*32+tok]=v[3];
    }
  }
  int tg = tid & 7, dg = tid >> 3;     // 8 tok-groups(4 tok) x 32 d-groups(8 d)
  float acc[4][8] = {};
  const float* wbase = Wo + (size_t)m * 65536;
  for (int c4 = 0; c4 < 4; ++c4) {
    __syncthreads();
#pragma unroll
    for (int i = 0; i < 16; ++i) {
      int f = tid + 256 * i;
      int cr = f >> 6, doff = (f & 63) * 4;
      *(f32x4*)&Wl[f * 4] = *(const f32x4*)(wbase + (size_t)(c4 * 64 + cr) * 256 + doff);
    }
    __syncthreads();
#pragma unroll 4
    for (int c = 0; c < 64; ++c) {
      f32x4 q4 = *(const f32x4*)&qT[(c4 * 64 + c) * 32 + tg * 4];
      f32x4 w0 = *(const f32x4*)&Wl[c * 256 + dg * 8];
      f32x4 w1 = *(const f32x4*)&Wl[c * 256 + dg * 8 + 4];
#pragma unroll
      for (int i = 0; i < 4; ++i) {
        acc[i][0]+=q4[i]*w0[0]; acc[i][1]+=q4[i]*w0[1]; acc[i][2]+=q4[i]*w0[2]; acc[i][3]+=q4[i]*w0[3];
        acc[i][4]+=q4[i]*w1[0]; acc[i][5]+=q4[i]*w1[1]; acc[i][6]+=q4[i]*w1[2]; acc[i][7]+=q4[i]*w1[3];
      }
    }
  }
#pragma unroll
  for (int i = 0; i < 4; ++i) {
    int t = t0 + tg * 4 + i;
    f32x4 lo, hi;
#pragma unroll
    for (int jj = 0; jj < 4; ++jj) {
      lo[jj] = acc[i][jj]     + bo[m * 256 + dg * 8 + jj];
      hi[jj] = acc[i][jj + 4] + bo[m * 256 + dg * 8 + 4 + jj];
    }
    float* dst = outp + (size_t)t * 2048 + m * 256 + dg * 8;
    *(f32x4*)(dst)     = lo;
    *(f32x4*)(dst + 4) = hi;
  }
  float lp = 0.0f;
  {
    int ltok = tid & 31, cg2 = tid >> 5;
    const float* xg = XH + (size_t)m * 2097152 + t0 + ltok;
    for (int c = cg2 * 32; c < cg2 * 32 + 32; ++c) {
      float qv = qT[c * 32 + ltok];
      float xv = xg[(size_t)c * 8192];
      float d = qv - xv; lp += d * d;
    }
  }
  red[tid] = (double)lp;
  __syncthreads();
  for (int off = 128; off; off >>= 1) { if (tid < off) red[tid] += red[tid + off]; __syncthreads(); }
  if (tid == 0) lossp[bx] = red[0];
}

// ---------- finalize loss (f32 at outp[16777216]) ----------
__global__ void k_final(const double* __restrict__ lossp, float* __restrict__ outp) {
  __shared__ double red[256];
  int tid = threadIdx.x;
  double s = 0.0;
  for (int i = 0; i < 8; ++i) s += lossp[tid + 256 * i];
  red[tid] = s; __syncthreads();
  for (int off = 128; off; off >>= 1) { if (tid < off) red[tid] += red[tid + off]; __syncthreads(); }
  if (tid == 0) outp[16777216] = (float)(1.25 * red[0] / 16777216.0);
}

// ---------- idx -> f32 ----------
__global__ void k_idxout(const int* __restrict__ idxp, float* __restrict__ outp) {
  int i = blockIdx.x * 256 + threadIdx.x;
  outp[16777217 + i] = (float)idxp[i];
}

extern "C" void kernel_launch(void* const* d_in, const int* in_sizes, int n_in,
                              void* d_out, int out_size, void* d_ws, size_t ws_size,
                              hipStream_t stream) {
  (void)in_sizes; (void)n_in; (void)out_size; (void)ws_size;
  const float* slots = (const float*)d_in[0];
  const float* Wp    = (const float*)d_in[1];
  const float* bp    = (const float*)d_in[2];
  const float* cb    = (const float*)d_in[3];
  const float* Wo    = (const float*)d_in[4];
  const float* bo    = (const float*)d_in[5];
  float* outp = (float*)d_out;
  char* ws = (char*)d_ws;
  double*         lossp = (double*)(ws + WS_LOSSP);
  float*          B32   = (float*)(ws + WS_B32);
  int*            idxp  = (int*)(ws + WS_IDX);
  int*            cnts  = (int*)(ws + WS_CNT);
  unsigned short* lists = (unsigned short*)(ws + WS_LST);
  float*          XH    = (float*)(ws + WS_XH);
  unsigned short* CBb   = (unsigned short*)(ws + WS_CBT);

  k_cbnormB<<<128,  256, 0, stream>>>(cb, B32);
  k_cbb    <<<4096, 256, 0, stream>>>(cb, CBb);
  k_xhat   <<<2048, 256, 0, stream>>>(slots, Wp, bp, XH);
  k_argmin <<<512,  256, 0, stream>>>(XH, CBb, B32, cnts, lists);
  k_select <<<1024, 256, 0, stream>>>(XH, cb, B32, cnts, lists, idxp);
  k_out    <<<2048, 256, 0, stream>>>(cb, Wo, bo, XH, idxp, outp, lossp);
  k_final  <<<1,    256, 0, stream>>>(lossp, outp);
  k_idxout <<<256,  256, 0, stream>>>(idxp, outp);
}